// Round 1
// baseline (633.565 us; speedup 1.0000x reference)
//
#include <hip/hip_runtime.h>
#include <math.h>

#define NN 100000
#define NE 800000
#define INC 128
#define HID 32
#define HEADS 8
#define C1 256   // HEADS*HID
#define OC 40
#define NEG 0.2f

static __device__ __forceinline__ float leaky(float v){ return v > 0.f ? v : NEG*v; }

// ---------------- K1: xp1 = x @ W1, plus per-(node,head) attention dots ----------------
// block = 256 thr; block tile = 32 rows x 256 cols; per-thread 4 rows x (4+4) cols.
__global__ __launch_bounds__(256) void k_gemm1(const float* __restrict__ x,
    const float* __restrict__ W1, const float* __restrict__ attS,
    const float* __restrict__ attD, float* __restrict__ xp1,
    float* __restrict__ asrc, float* __restrict__ adst)
{
  __shared__ float xs[32*128];   // 16 KB
  __shared__ float ws[32*256];   // 32 KB per k-tile
  const int tid  = threadIdx.x;
  const int tcol = tid & 31;     // 32 col-groups (4 cols each, two halves)
  const int trow = tid >> 5;     // 8 row-groups (4 rows each)
  const int r0   = blockIdx.x * 32;   // 3125*32 == 100000 exactly

  { // stage x tile [32 rows x 128 k]
    const float4* xg  = (const float4*)x + (size_t)r0 * 32;
    float4* xs4 = (float4*)xs;
    #pragma unroll
    for (int i = 0; i < 4; ++i) xs4[i*256 + tid] = xg[i*256 + tid];
  }

  float4 acc0[4], acc1[4];
  #pragma unroll
  for (int r = 0; r < 4; ++r) { acc0[r] = make_float4(0,0,0,0); acc1[r] = make_float4(0,0,0,0); }

  for (int kt = 0; kt < 4; ++kt) {
    __syncthreads();
    { // stage W1 k-tile [32 k x 256 cols]
      const float4* wg = (const float4*)W1 + (size_t)kt*32*64;
      float4* ws4 = (float4*)ws;
      #pragma unroll
      for (int i = 0; i < 8; ++i) ws4[i*256 + tid] = wg[i*256 + tid];
    }
    __syncthreads();
    const float4* ws4 = (const float4*)ws;
    const float4* xs4 = (const float4*)xs;
    #pragma unroll
    for (int kk4 = 0; kk4 < 8; ++kk4) {
      float4 xv[4];
      #pragma unroll
      for (int r = 0; r < 4; ++r) xv[r] = xs4[(trow*4 + r)*32 + kt*8 + kk4];
      #pragma unroll
      for (int i = 0; i < 4; ++i) {
        const int kk = kk4*4 + i;
        float4 w0 = ws4[kk*64 + tcol];        // cols 4*tcol..+3
        float4 w1 = ws4[kk*64 + 32 + tcol];   // cols 128+4*tcol..+3
        #pragma unroll
        for (int r = 0; r < 4; ++r) {
          float xvs = ((const float*)&xv[r])[i];
          acc0[r].x += xvs*w0.x; acc0[r].y += xvs*w0.y; acc0[r].z += xvs*w0.z; acc0[r].w += xvs*w0.w;
          acc1[r].x += xvs*w1.x; acc1[r].y += xvs*w1.y; acc1[r].z += xvs*w1.z; acc1[r].w += xvs*w1.w;
        }
      }
    }
  }

  // epilogue: store xp1 + attention head-dots
  float4* xp4 = (float4*)xp1;
  const int h0 = tcol >> 3;       // head of col half 0 (0..3); half 1 is h0+4
  const int hq = tcol & 7;        // position group within head
  #pragma unroll
  for (int r = 0; r < 4; ++r) {
    const int row = r0 + trow*4 + r;
    xp4[(size_t)row*64 + tcol]      = acc0[r];
    xp4[(size_t)row*64 + 32 + tcol] = acc1[r];
    float s0=0.f, s1=0.f, d0=0.f, d1=0.f;
    #pragma unroll
    for (int i = 0; i < 4; ++i) {
      float a0 = ((const float*)&acc0[r])[i];
      float a1 = ((const float*)&acc1[r])[i];
      int cih = hq*4 + i;   // col within head
      s0 += a0 * attS[h0*32 + cih];
      s1 += a1 * attS[(4+h0)*32 + cih];
      d0 += a0 * attD[h0*32 + cih];
      d1 += a1 * attD[(4+h0)*32 + cih];
    }
    #pragma unroll
    for (int off = 1; off < 8; off <<= 1) {
      s0 += __shfl_xor(s0, off, 64);
      s1 += __shfl_xor(s1, off, 64);
      d0 += __shfl_xor(d0, off, 64);
      d1 += __shfl_xor(d1, off, 64);
    }
    if (hq == 0) {
      asrc[row*8 + h0]     = s0;
      asrc[row*8 + 4 + h0] = s1;
      adst[row*8 + h0]     = d0;
      adst[row*8 + 4 + h0] = d1;
    }
  }
}

// ---------------- CSR build (dst-sorted), self-loop slot reserved via deg init = 1 ----------------
__global__ __launch_bounds__(256) void k_deg_init(int* deg){
  int i = blockIdx.x*256 + threadIdx.x;
  if (i < NN) deg[i] = 1;
}
__global__ __launch_bounds__(256) void k_deg_count(const int* __restrict__ ei, int* deg){
  int i = blockIdx.x*256 + threadIdx.x;
  if (i < NE) atomicAdd(&deg[ei[NE + i]], 1);
}
__global__ __launch_bounds__(256) void k_scan1(const int* __restrict__ deg, int* part, int* bsum){
  __shared__ int lds[256];
  const int t = threadIdx.x;
  const int base = blockIdx.x*1024;
  int v[4]; int s = 0;
  #pragma unroll
  for (int i = 0; i < 4; ++i){ int idx = base + t*4 + i; v[i] = (idx < NN) ? deg[idx] : 0; s += v[i]; }
  lds[t] = s; __syncthreads();
  for (int off = 1; off < 256; off <<= 1){
    int xx = (t >= off) ? lds[t-off] : 0;
    __syncthreads();
    lds[t] += xx;
    __syncthreads();
  }
  int excl = lds[t] - s;
  #pragma unroll
  for (int i = 0; i < 4; ++i){ int idx = base + t*4 + i; if (idx < NN) part[idx] = excl; excl += v[i]; }
  if (t == 255) bsum[blockIdx.x] = lds[255];
}
__global__ void k_scan2(const int* __restrict__ bsum, int* boff){
  if (threadIdx.x == 0 && blockIdx.x == 0){
    int run = 0;
    for (int i = 0; i < 98; ++i){ boff[i] = run; run += bsum[i]; }
  }
}
__global__ __launch_bounds__(256) void k_scan3(const int* __restrict__ part, const int* __restrict__ boff,
                                               int* rowptr, int* cursor){
  int i = blockIdx.x*256 + threadIdx.x;
  if (i < NN){ int v = part[i] + boff[i >> 10]; rowptr[i] = v; cursor[i] = v; }
  if (i == 0) rowptr[NN] = NN + NE;
}
__global__ __launch_bounds__(256) void k_fill(const int* __restrict__ ei, int* cursor, int* __restrict__ esrc){
  int i = blockIdx.x*256 + threadIdx.x;
  if (i < NE + NN){
    int s, d;
    if (i < NE){ s = ei[i]; d = ei[NE + i]; } else { s = d = i - NE; }
    int slot = atomicAdd(&cursor[d], 1);
    esrc[slot] = s;
  }
}

// ---------------- K3: layer-1 aggregation + bias + ReLU. One wave per dst node ----------------
__global__ __launch_bounds__(256) void k_agg1(const float* __restrict__ xp1,
    const float* __restrict__ asrc, const float* __restrict__ adst,
    const float* __restrict__ b1, const int* __restrict__ rowptr,
    const int* __restrict__ esrc, float* __restrict__ h1)
{
  const int lane = threadIdx.x & 63;
  int n = __builtin_amdgcn_readfirstlane(blockIdx.x*4 + (threadIdx.x >> 6));
  const int h = lane >> 3;                 // head 0..7 (lane covers channels lane*4..+3)
  const float ad = adst[n*8 + h];
  const int jb = rowptr[n], je = rowptr[n+1];
  const float4* xp4 = (const float4*)xp1;
  float4 acc = make_float4(0,0,0,0);
  float z = 0.f;
  for (int j = jb; j < je; ++j) {
    int s = esrc[j];
    float p = __expf(leaky(asrc[s*8 + h] + ad));
    z += p;
    float4 xv = xp4[(size_t)s*64 + lane];
    acc.x += p*xv.x; acc.y += p*xv.y; acc.z += p*xv.z; acc.w += p*xv.w;
  }
  const float inv = 1.f / (z + 1e-16f);
  const float4 bb = ((const float4*)b1)[lane];
  float4 o;
  o.x = fmaxf(acc.x*inv + bb.x, 0.f);
  o.y = fmaxf(acc.y*inv + bb.y, 0.f);
  o.z = fmaxf(acc.z*inv + bb.z, 0.f);
  o.w = fmaxf(acc.w*inv + bb.w, 0.f);
  ((float4*)h1)[(size_t)n*64 + lane] = o;
}

// ---------------- K4: xp2 = h1 @ W2 (+ layer-2 attention dots). lane == row, W2 via s_load ----------------
__global__ __launch_bounds__(256) void k_gemm2(const float* __restrict__ h1,
    const float* __restrict__ W2, const float* __restrict__ attS,
    const float* __restrict__ attD, float* __restrict__ xp2,
    float* __restrict__ asrc2, float* __restrict__ adst2)
{
  __shared__ float hs[256*33];   // +1 pad: conflict-free per-row reads
  const int tid = threadIdx.x;
  const int r0  = blockIdx.x * 256;
  const int row = r0 + tid;
  float acc[OC];
  #pragma unroll
  for (int c = 0; c < OC; ++c) acc[c] = 0.f;

  for (int kt = 0; kt < 8; ++kt) {
    __syncthreads();
    for (int i = 0; i < 32; ++i) {
      int flat = i*256 + tid;
      int rr = flat >> 5, cc = flat & 31;
      float v = (r0 + rr < NN) ? h1[(size_t)(r0 + rr)*256 + kt*32 + cc] : 0.f;
      hs[rr*33 + cc] = v;
    }
    __syncthreads();
    #pragma unroll 4
    for (int kk = 0; kk < 32; ++kk) {
      float hv = hs[tid*33 + kk];
      const int k = kt*32 + kk;           // uniform -> W2 reads become s_load
      #pragma unroll
      for (int c = 0; c < OC; ++c) acc[c] += hv * W2[k*OC + c];
    }
  }

  if (row < NN) {
    float s2 = 0.f, d2 = 0.f;
    #pragma unroll
    for (int c = 0; c < OC; ++c){ s2 += acc[c]*attS[c]; d2 += acc[c]*attD[c]; }
    asrc2[row] = s2; adst2[row] = d2;
    float4* o4 = (float4*)(xp2 + (size_t)row*OC);
    #pragma unroll
    for (int i = 0; i < 10; ++i) o4[i] = make_float4(acc[i*4], acc[i*4+1], acc[i*4+2], acc[i*4+3]);
  }
}

// ---------------- K5: layer-2 aggregation + bias + log_softmax. One wave per node ----------------
__global__ __launch_bounds__(256) void k_agg2(const float* __restrict__ xp2,
    const float* __restrict__ asrc2, const float* __restrict__ adst2,
    const float* __restrict__ b2, const int* __restrict__ rowptr,
    const int* __restrict__ esrc, float* __restrict__ out)
{
  const int lane = threadIdx.x & 63;
  int n = __builtin_amdgcn_readfirstlane(blockIdx.x*4 + (threadIdx.x >> 6));
  const float ad = adst2[n];
  const int jb = rowptr[n], je = rowptr[n+1];
  const bool act = lane < OC;
  float acc = 0.f, z = 0.f;
  for (int j = jb; j < je; ++j) {
    int s = esrc[j];
    float p = __expf(leaky(asrc2[s] + ad));
    z += p;
    if (act) acc += p * xp2[(size_t)s*OC + lane];
  }
  float val = act ? (acc/(z + 1e-16f) + b2[lane]) : -INFINITY;
  float m = val;
  #pragma unroll
  for (int off = 32; off > 0; off >>= 1) m = fmaxf(m, __shfl_xor(m, off, 64));
  float e = act ? __expf(val - m) : 0.f;
  float sum = e;
  #pragma unroll
  for (int off = 32; off > 0; off >>= 1) sum += __shfl_xor(sum, off, 64);
  if (act) out[(size_t)n*OC + lane] = val - m - __logf(sum);
}

extern "C" void kernel_launch(void* const* d_in, const int* in_sizes, int n_in,
                              void* d_out, int out_size, void* d_ws, size_t ws_size,
                              hipStream_t stream)
{
  const float* x   = (const float*)d_in[0];
  const int*   ei  = (const int*)  d_in[1];
  const float* W1  = (const float*)d_in[2];
  const float* aS1 = (const float*)d_in[3];
  const float* aD1 = (const float*)d_in[4];
  const float* b1  = (const float*)d_in[5];
  const float* W2  = (const float*)d_in[6];
  const float* aS2 = (const float*)d_in[7];
  const float* aD2 = (const float*)d_in[8];
  const float* b2  = (const float*)d_in[9];
  float* out = (float*)d_out;

  char* w = (char*)d_ws;
  size_t off = 0;
  auto alloc = [&](size_t bytes){ void* p = w + off; off += (bytes + 255) & ~(size_t)255; return p; };
  float* xp1  = (float*)alloc((size_t)NN*C1*4);     // reused as xp2 after agg1
  float* h1   = (float*)alloc((size_t)NN*C1*4);
  float* as1  = (float*)alloc((size_t)NN*8*4);
  float* ad1  = (float*)alloc((size_t)NN*8*4);
  float* as2  = (float*)alloc((size_t)NN*4);
  float* ad2  = (float*)alloc((size_t)NN*4);
  int* deg    = (int*)alloc((size_t)NN*4);
  int* part   = (int*)alloc((size_t)NN*4);
  int* rowptr = (int*)alloc((size_t)(NN+1)*4);
  int* cursor = (int*)alloc((size_t)NN*4);
  int* bsum   = (int*)alloc(98*4);
  int* boff   = (int*)alloc(98*4);
  int* esrc   = (int*)alloc((size_t)(NN+NE)*4);
  float* xp2  = xp1;
  (void)ws_size; (void)in_sizes; (void)n_in; (void)out_size;

  k_gemm1    <<<3125, 256, 0, stream>>>(x, W1, aS1, aD1, xp1, as1, ad1);
  k_deg_init <<<391,  256, 0, stream>>>(deg);
  k_deg_count<<<3125, 256, 0, stream>>>(ei, deg);
  k_scan1    <<<98,   256, 0, stream>>>(deg, part, bsum);
  k_scan2    <<<1,    64,  0, stream>>>(bsum, boff);
  k_scan3    <<<391,  256, 0, stream>>>(part, boff, rowptr, cursor);
  k_fill     <<<3516, 256, 0, stream>>>(ei, cursor, esrc);
  k_agg1     <<<25000,256, 0, stream>>>(xp1, as1, ad1, b1, rowptr, esrc, h1);
  k_gemm2    <<<391,  256, 0, stream>>>(h1, W2, aS2, aD2, xp2, as2, ad2);
  k_agg2     <<<25000,256, 0, stream>>>(xp2, as2, ad2, b2, rowptr, esrc, out);
}

// Round 2
// 540.668 us; speedup vs baseline: 1.1718x; 1.1718x over previous
//
#include <hip/hip_runtime.h>
#include <math.h>

#define NN 100000
#define NE 800000
#define INC 128
#define HID 32
#define HEADS 8
#define C1 256   // HEADS*HID
#define OC 40
#define NEG 0.2f

typedef _Float16 h4 __attribute__((ext_vector_type(4)));

static __device__ __forceinline__ float leaky(float v){ return v > 0.f ? v : NEG*v; }

// ---------------- K1: xp1 = x @ W1 (fp16 out), plus per-(node,head) attention dots ----------------
// block = 256 thr; block tile = 32 rows x 256 cols; per-thread 4 rows x (4+4) cols.
__global__ __launch_bounds__(256) void k_gemm1(const float* __restrict__ x,
    const float* __restrict__ W1, const float* __restrict__ attS,
    const float* __restrict__ attD, _Float16* __restrict__ xp1,
    float* __restrict__ asrc, float* __restrict__ adst)
{
  __shared__ float xs[32*128];   // 16 KB
  __shared__ float ws[32*256];   // 32 KB per k-tile
  const int tid  = threadIdx.x;
  const int tcol = tid & 31;     // 32 col-groups (4 cols each, two halves)
  const int trow = tid >> 5;     // 8 row-groups (4 rows each)
  const int r0   = blockIdx.x * 32;   // 3125*32 == 100000 exactly

  { // stage x tile [32 rows x 128 k]
    const float4* xg  = (const float4*)x + (size_t)r0 * 32;
    float4* xs4 = (float4*)xs;
    #pragma unroll
    for (int i = 0; i < 4; ++i) xs4[i*256 + tid] = xg[i*256 + tid];
  }

  float4 acc0[4], acc1[4];
  #pragma unroll
  for (int r = 0; r < 4; ++r) { acc0[r] = make_float4(0,0,0,0); acc1[r] = make_float4(0,0,0,0); }

  for (int kt = 0; kt < 4; ++kt) {
    __syncthreads();
    { // stage W1 k-tile [32 k x 256 cols]
      const float4* wg = (const float4*)W1 + (size_t)kt*32*64;
      float4* ws4 = (float4*)ws;
      #pragma unroll
      for (int i = 0; i < 8; ++i) ws4[i*256 + tid] = wg[i*256 + tid];
    }
    __syncthreads();
    const float4* ws4 = (const float4*)ws;
    const float4* xs4 = (const float4*)xs;
    #pragma unroll
    for (int kk4 = 0; kk4 < 8; ++kk4) {
      float4 xv[4];
      #pragma unroll
      for (int r = 0; r < 4; ++r) xv[r] = xs4[(trow*4 + r)*32 + kt*8 + kk4];
      #pragma unroll
      for (int i = 0; i < 4; ++i) {
        const int kk = kk4*4 + i;
        float4 w0 = ws4[kk*64 + tcol];        // cols 4*tcol..+3
        float4 w1 = ws4[kk*64 + 32 + tcol];   // cols 128+4*tcol..+3
        #pragma unroll
        for (int r = 0; r < 4; ++r) {
          float xvs = ((const float*)&xv[r])[i];
          acc0[r].x += xvs*w0.x; acc0[r].y += xvs*w0.y; acc0[r].z += xvs*w0.z; acc0[r].w += xvs*w0.w;
          acc1[r].x += xvs*w1.x; acc1[r].y += xvs*w1.y; acc1[r].z += xvs*w1.z; acc1[r].w += xvs*w1.w;
        }
      }
    }
  }

  // epilogue: store xp1 (fp16) + attention head-dots (f32)
  h4* xph = (h4*)xp1;
  const int h0 = tcol >> 3;       // head of col half 0 (0..3); half 1 is h0+4
  const int hq = tcol & 7;        // position group within head
  #pragma unroll
  for (int r = 0; r < 4; ++r) {
    const int row = r0 + trow*4 + r;
    h4 o0 = {(_Float16)acc0[r].x, (_Float16)acc0[r].y, (_Float16)acc0[r].z, (_Float16)acc0[r].w};
    h4 o1 = {(_Float16)acc1[r].x, (_Float16)acc1[r].y, (_Float16)acc1[r].z, (_Float16)acc1[r].w};
    xph[(size_t)row*64 + tcol]      = o0;
    xph[(size_t)row*64 + 32 + tcol] = o1;
    float s0=0.f, s1=0.f, d0=0.f, d1=0.f;
    #pragma unroll
    for (int i = 0; i < 4; ++i) {
      float a0 = ((const float*)&acc0[r])[i];
      float a1 = ((const float*)&acc1[r])[i];
      int cih = hq*4 + i;   // col within head
      s0 += a0 * attS[h0*32 + cih];
      s1 += a1 * attS[(4+h0)*32 + cih];
      d0 += a0 * attD[h0*32 + cih];
      d1 += a1 * attD[(4+h0)*32 + cih];
    }
    #pragma unroll
    for (int off = 1; off < 8; off <<= 1) {
      s0 += __shfl_xor(s0, off, 64);
      s1 += __shfl_xor(s1, off, 64);
      d0 += __shfl_xor(d0, off, 64);
      d1 += __shfl_xor(d1, off, 64);
    }
    if (hq == 0) {
      asrc[row*8 + h0]     = s0;
      asrc[row*8 + 4 + h0] = s1;
      adst[row*8 + h0]     = d0;
      adst[row*8 + 4 + h0] = d1;
    }
  }
}

// ---------------- CSR build (dst-sorted), self-loop slot reserved via deg init = 1 ----------------
__global__ __launch_bounds__(256) void k_deg_init(int* deg){
  int i = blockIdx.x*256 + threadIdx.x;
  if (i < NN) deg[i] = 1;
}
__global__ __launch_bounds__(256) void k_deg_count(const int* __restrict__ ei, int* deg){
  int i = blockIdx.x*256 + threadIdx.x;
  if (i < NE) atomicAdd(&deg[ei[NE + i]], 1);
}
__global__ __launch_bounds__(256) void k_scan1(const int* __restrict__ deg, int* part, int* bsum){
  __shared__ int lds[256];
  const int t = threadIdx.x;
  const int base = blockIdx.x*1024;
  int v[4]; int s = 0;
  #pragma unroll
  for (int i = 0; i < 4; ++i){ int idx = base + t*4 + i; v[i] = (idx < NN) ? deg[idx] : 0; s += v[i]; }
  lds[t] = s; __syncthreads();
  for (int off = 1; off < 256; off <<= 1){
    int xx = (t >= off) ? lds[t-off] : 0;
    __syncthreads();
    lds[t] += xx;
    __syncthreads();
  }
  int excl = lds[t] - s;
  #pragma unroll
  for (int i = 0; i < 4; ++i){ int idx = base + t*4 + i; if (idx < NN) part[idx] = excl; excl += v[i]; }
  if (t == 255) bsum[blockIdx.x] = lds[255];
}
__global__ void k_scan2(const int* __restrict__ bsum, int* boff){
  if (threadIdx.x == 0 && blockIdx.x == 0){
    int run = 0;
    for (int i = 0; i < 98; ++i){ boff[i] = run; run += bsum[i]; }
  }
}
__global__ __launch_bounds__(256) void k_scan3(const int* __restrict__ part, const int* __restrict__ boff,
                                               int* rowptr, int* cursor){
  int i = blockIdx.x*256 + threadIdx.x;
  if (i < NN){ int v = part[i] + boff[i >> 10]; rowptr[i] = v; cursor[i] = v; }
  if (i == 0) rowptr[NN] = NN + NE;
}
__global__ __launch_bounds__(256) void k_fill(const int* __restrict__ ei, int* cursor, int* __restrict__ esrc){
  int i = blockIdx.x*256 + threadIdx.x;
  if (i < NE + NN){
    int s, d;
    if (i < NE){ s = ei[i]; d = ei[NE + i]; } else { s = d = i - NE; }
    int slot = atomicAdd(&cursor[d], 1);
    esrc[slot] = s;
  }
}

// ---------------- K3: layer-1 aggregation + bias + ReLU. One wave per dst node ----------------
__global__ __launch_bounds__(256) void k_agg1(const _Float16* __restrict__ xp1,
    const float* __restrict__ asrc, const float* __restrict__ adst,
    const float* __restrict__ b1, const int* __restrict__ rowptr,
    const int* __restrict__ esrc, _Float16* __restrict__ h1)
{
  const int lane = threadIdx.x & 63;
  int n = __builtin_amdgcn_readfirstlane(blockIdx.x*4 + (threadIdx.x >> 6));
  const int h = lane >> 3;                 // head 0..7 (lane covers channels lane*4..+3)
  const float ad = adst[n*8 + h];
  const int jb = rowptr[n], je = rowptr[n+1];
  const h4* xph = (const h4*)xp1;
  float4 acc = make_float4(0,0,0,0);
  float z = 0.f;
  for (int j = jb; j < je; ++j) {
    int s = esrc[j];
    float p = __expf(leaky(asrc[s*8 + h] + ad));
    z += p;
    h4 xv = xph[(size_t)s*64 + lane];
    acc.x += p*(float)xv.x; acc.y += p*(float)xv.y;
    acc.z += p*(float)xv.z; acc.w += p*(float)xv.w;
  }
  const float inv = 1.f / (z + 1e-16f);
  const float4 bb = ((const float4*)b1)[lane];
  h4 o = {(_Float16)fmaxf(acc.x*inv + bb.x, 0.f),
          (_Float16)fmaxf(acc.y*inv + bb.y, 0.f),
          (_Float16)fmaxf(acc.z*inv + bb.z, 0.f),
          (_Float16)fmaxf(acc.w*inv + bb.w, 0.f)};
  ((h4*)h1)[(size_t)n*64 + lane] = o;
}

// ---------------- K4: xp2 = h1 @ W2 (+ layer-2 attention dots). lane == row, W2 via s_load ----------------
__global__ __launch_bounds__(256) void k_gemm2(const _Float16* __restrict__ h1,
    const float* __restrict__ W2, const float* __restrict__ attS,
    const float* __restrict__ attD, _Float16* __restrict__ xp2,
    float* __restrict__ asrc2, float* __restrict__ adst2)
{
  __shared__ float hs[256*33];   // +1 pad: conflict-free per-row reads
  const int tid = threadIdx.x;
  const int r0  = blockIdx.x * 256;
  const int row = r0 + tid;
  const h4* h1h = (const h4*)h1;
  float acc[OC];
  #pragma unroll
  for (int c = 0; c < OC; ++c) acc[c] = 0.f;

  for (int kt = 0; kt < 8; ++kt) {
    __syncthreads();
    #pragma unroll
    for (int i = 0; i < 8; ++i) {       // 2048 h4 units = 256 rows x 8 h4
      int flat = i*256 + tid;
      int rr = flat >> 3, hc = flat & 7;
      h4 v; v.x = v.y = v.z = v.w = (_Float16)0;
      if (r0 + rr < NN) v = h1h[(size_t)(r0 + rr)*64 + kt*8 + hc];
      hs[rr*33 + hc*4 + 0] = (float)v.x;
      hs[rr*33 + hc*4 + 1] = (float)v.y;
      hs[rr*33 + hc*4 + 2] = (float)v.z;
      hs[rr*33 + hc*4 + 3] = (float)v.w;
    }
    __syncthreads();
    #pragma unroll 4
    for (int kk = 0; kk < 32; ++kk) {
      float hv = hs[tid*33 + kk];
      const int k = kt*32 + kk;           // uniform -> W2 reads become s_load
      #pragma unroll
      for (int c = 0; c < OC; ++c) acc[c] += hv * W2[k*OC + c];
    }
  }

  if (row < NN) {
    float s2 = 0.f, d2 = 0.f;
    #pragma unroll
    for (int c = 0; c < OC; ++c){ s2 += acc[c]*attS[c]; d2 += acc[c]*attD[c]; }
    asrc2[row] = s2; adst2[row] = d2;
    h4* o4 = (h4*)(xp2 + (size_t)row*OC);
    #pragma unroll
    for (int i = 0; i < 10; ++i) {
      h4 ov = {(_Float16)acc[i*4], (_Float16)acc[i*4+1], (_Float16)acc[i*4+2], (_Float16)acc[i*4+3]};
      o4[i] = ov;
    }
  }
}

// ---------------- K5: layer-2 aggregation + bias + log_softmax. One wave per node ----------------
__global__ __launch_bounds__(256) void k_agg2(const _Float16* __restrict__ xp2,
    const float* __restrict__ asrc2, const float* __restrict__ adst2,
    const float* __restrict__ b2, const int* __restrict__ rowptr,
    const int* __restrict__ esrc, float* __restrict__ out)
{
  const int lane = threadIdx.x & 63;
  int n = __builtin_amdgcn_readfirstlane(blockIdx.x*4 + (threadIdx.x >> 6));
  const float ad = adst2[n];
  const int jb = rowptr[n], je = rowptr[n+1];
  const bool act = lane < OC;
  float acc = 0.f, z = 0.f;
  for (int j = jb; j < je; ++j) {
    int s = esrc[j];
    float p = __expf(leaky(asrc2[s] + ad));
    z += p;
    if (act) acc += p * (float)xp2[(size_t)s*OC + lane];
  }
  float val = act ? (acc/(z + 1e-16f) + b2[lane]) : -INFINITY;
  float m = val;
  #pragma unroll
  for (int off = 32; off > 0; off >>= 1) m = fmaxf(m, __shfl_xor(m, off, 64));
  float e = act ? __expf(val - m) : 0.f;
  float sum = e;
  #pragma unroll
  for (int off = 32; off > 0; off >>= 1) sum += __shfl_xor(sum, off, 64);
  if (act) out[(size_t)n*OC + lane] = val - m - __logf(sum);
}

extern "C" void kernel_launch(void* const* d_in, const int* in_sizes, int n_in,
                              void* d_out, int out_size, void* d_ws, size_t ws_size,
                              hipStream_t stream)
{
  const float* x   = (const float*)d_in[0];
  const int*   ei  = (const int*)  d_in[1];
  const float* W1  = (const float*)d_in[2];
  const float* aS1 = (const float*)d_in[3];
  const float* aD1 = (const float*)d_in[4];
  const float* b1  = (const float*)d_in[5];
  const float* W2  = (const float*)d_in[6];
  const float* aS2 = (const float*)d_in[7];
  const float* aD2 = (const float*)d_in[8];
  const float* b2  = (const float*)d_in[9];
  float* out = (float*)d_out;

  char* w = (char*)d_ws;
  size_t off = 0;
  auto alloc = [&](size_t bytes){ void* p = w + off; off += (bytes + 255) & ~(size_t)255; return p; };
  _Float16* xp1 = (_Float16*)alloc((size_t)NN*C1*2);   // fp16; reused as xp2 after agg1
  _Float16* h1  = (_Float16*)alloc((size_t)NN*C1*2);   // fp16
  float* as1  = (float*)alloc((size_t)NN*8*4);
  float* ad1  = (float*)alloc((size_t)NN*8*4);
  float* as2  = (float*)alloc((size_t)NN*4);
  float* ad2  = (float*)alloc((size_t)NN*4);
  int* deg    = (int*)alloc((size_t)NN*4);
  int* part   = (int*)alloc((size_t)NN*4);
  int* rowptr = (int*)alloc((size_t)(NN+1)*4);
  int* cursor = (int*)alloc((size_t)NN*4);
  int* bsum   = (int*)alloc(98*4);
  int* boff   = (int*)alloc(98*4);
  int* esrc   = (int*)alloc((size_t)(NN+NE)*4);
  _Float16* xp2 = xp1;
  (void)ws_size; (void)in_sizes; (void)n_in; (void)out_size;

  k_gemm1    <<<3125, 256, 0, stream>>>(x, W1, aS1, aD1, xp1, as1, ad1);
  k_deg_init <<<391,  256, 0, stream>>>(deg);
  k_deg_count<<<3125, 256, 0, stream>>>(ei, deg);
  k_scan1    <<<98,   256, 0, stream>>>(deg, part, bsum);
  k_scan2    <<<1,    64,  0, stream>>>(bsum, boff);
  k_scan3    <<<391,  256, 0, stream>>>(part, boff, rowptr, cursor);
  k_fill     <<<3516, 256, 0, stream>>>(ei, cursor, esrc);
  k_agg1     <<<25000,256, 0, stream>>>(xp1, as1, ad1, b1, rowptr, esrc, h1);
  k_gemm2    <<<391,  256, 0, stream>>>(h1, W2, aS2, aD2, xp2, as2, ad2);
  k_agg2     <<<25000,256, 0, stream>>>(xp2, as2, ad2, b2, rowptr, esrc, out);
}

// Round 3
// 442.515 us; speedup vs baseline: 1.4317x; 1.2218x over previous
//
#include <hip/hip_runtime.h>
#include <math.h>

#define NN 100000
#define NE 800000
#define C1 256   // HEADS*HID
#define OC 40
#define NEG 0.2f

typedef _Float16 h4 __attribute__((ext_vector_type(4)));
typedef _Float16 h8 __attribute__((ext_vector_type(8)));
typedef float f4v __attribute__((ext_vector_type(4)));

static __device__ __forceinline__ float leaky(float v){ return v > 0.f ? v : NEG*v; }

static __device__ __forceinline__ h8 cvt8(const float4* p){
  float4 a = p[0], b = p[1];
  h8 r = {(_Float16)a.x,(_Float16)a.y,(_Float16)a.z,(_Float16)a.w,
          (_Float16)b.x,(_Float16)b.y,(_Float16)b.z,(_Float16)b.w};
  return r;
}

// ---------------- tiny weight transposes (fp16) ----------------
__global__ __launch_bounds__(256) void k_w1t(const float* __restrict__ W1, _Float16* __restrict__ W1t){
  int k = blockIdx.x;        // 128
  int nb = threadIdx.x;      // 256
  W1t[(size_t)nb*128 + k] = (_Float16)W1[k*256 + nb];
}
__global__ __launch_bounds__(256) void k_w2t(const float* __restrict__ W2, _Float16* __restrict__ W2t){
  int nb = blockIdx.x;       // 48 (pad 40->48 with zeros)
  int k = threadIdx.x;       // 256
  float v = (nb < OC) ? W2[(size_t)k*OC + nb] : 0.f;
  W2t[(size_t)nb*256 + k] = (_Float16)v;
}

// ---------------- K1: xp1 = x @ W1 via fp16 MFMA + fused attention dots ----------------
// block = 4 waves; wave (wr,wc): rows r0+wr*32 (2 row-tiles), cols wc*128 (8 col-tiles).
__global__ __launch_bounds__(256) void k_gemm1(const float* __restrict__ x,
    const _Float16* __restrict__ W1t, const float* __restrict__ attS,
    const float* __restrict__ attD, _Float16* __restrict__ xp1,
    float* __restrict__ asrc, float* __restrict__ adst)
{
  const int tid  = threadIdx.x;
  const int lane = tid & 63;
  const int w    = tid >> 6;
  const int wr = w >> 1, wc = w & 1;
  const int n = lane & 15, quad = lane >> 4;
  const int r0 = blockIdx.x * 64;

  // per-lane attention coefficients (col = wc*128 + ct*16 + n), loop-invariant
  float aSc[8], aDc[8];
  #pragma unroll
  for (int ct = 0; ct < 8; ++ct){
    int col = wc*128 + ct*16 + n;
    aSc[ct] = attS[col]; aDc[ct] = attD[col];
  }

  f4v acc[2][8];
  #pragma unroll
  for (int rt = 0; rt < 2; ++rt)
    #pragma unroll
    for (int ct = 0; ct < 8; ++ct) acc[rt][ct] = (f4v){0.f,0.f,0.f,0.f};

  const int row0 = r0 + wr*32 + n;
  const int ra = (row0      < NN) ? row0      : NN-1;   // clamp: garbage masked at store
  const int rb = (row0 + 16 < NN) ? row0 + 16 : NN-1;

  #pragma unroll
  for (int ks = 0; ks < 4; ++ks){
    h8 a0 = cvt8((const float4*)(x + (size_t)ra*128 + ks*32 + quad*8));
    h8 a1 = cvt8((const float4*)(x + (size_t)rb*128 + ks*32 + quad*8));
    #pragma unroll
    for (int ct = 0; ct < 8; ++ct){
      h8 b = *(const h8*)(W1t + (size_t)(wc*128 + ct*16 + n)*128 + ks*32 + quad*8);
      acc[0][ct] = __builtin_amdgcn_mfma_f32_16x16x32_f16(a0, b, acc[0][ct], 0, 0, 0);
      acc[1][ct] = __builtin_amdgcn_mfma_f32_16x16x32_f16(a1, b, acc[1][ct], 0, 0, 0);
    }
  }

  // epilogue: D layout col = lane&15 (+ct*16), row = quad*4 + reg (+rt*16)
  #pragma unroll
  for (int rt = 0; rt < 2; ++rt){
    #pragma unroll
    for (int reg = 0; reg < 4; ++reg){
      const int row = r0 + wr*32 + rt*16 + quad*4 + reg;
      const bool ok = row < NN;
      float v[8];
      #pragma unroll
      for (int ct = 0; ct < 8; ++ct) v[ct] = acc[rt][ct][reg];
      if (ok){
        _Float16* xr = xp1 + (size_t)row*256 + wc*128 + n;
        #pragma unroll
        for (int ct = 0; ct < 8; ++ct) xr[ct*16] = (_Float16)v[ct];
      }
      // head h (of this wave's 4): cols 2h*16 .. 2h*16+31
      float s[4], d[4];
      #pragma unroll
      for (int h = 0; h < 4; ++h){
        s[h] = v[2*h]*aSc[2*h] + v[2*h+1]*aSc[2*h+1];
        d[h] = v[2*h]*aDc[2*h] + v[2*h+1]*aDc[2*h+1];
      }
      #pragma unroll
      for (int off = 1; off < 16; off <<= 1){
        #pragma unroll
        for (int h = 0; h < 4; ++h){
          s[h] += __shfl_xor(s[h], off, 64);
          d[h] += __shfl_xor(d[h], off, 64);
        }
      }
      if (ok && n == 0){
        #pragma unroll
        for (int h = 0; h < 4; ++h){
          asrc[row*8 + wc*4 + h] = s[h];
          adst[row*8 + wc*4 + h] = d[h];
        }
      }
    }
  }
}

// ---------------- CSR build (dst-sorted), self-loop slot reserved via deg init = 1 ----------------
__global__ __launch_bounds__(256) void k_deg_init(int* deg){
  int i = blockIdx.x*256 + threadIdx.x;
  if (i < NN) deg[i] = 1;
}
__global__ __launch_bounds__(256) void k_deg_count(const int* __restrict__ ei, int* deg){
  int i = blockIdx.x*256 + threadIdx.x;
  if (i < NE) atomicAdd(&deg[ei[NE + i]], 1);
}
__global__ __launch_bounds__(256) void k_scan1(const int* __restrict__ deg, int* part, int* bsum){
  __shared__ int lds[256];
  const int t = threadIdx.x;
  const int base = blockIdx.x*1024;
  int v[4]; int s = 0;
  #pragma unroll
  for (int i = 0; i < 4; ++i){ int idx = base + t*4 + i; v[i] = (idx < NN) ? deg[idx] : 0; s += v[i]; }
  lds[t] = s; __syncthreads();
  for (int off = 1; off < 256; off <<= 1){
    int xx = (t >= off) ? lds[t-off] : 0;
    __syncthreads();
    lds[t] += xx;
    __syncthreads();
  }
  int excl = lds[t] - s;
  #pragma unroll
  for (int i = 0; i < 4; ++i){ int idx = base + t*4 + i; if (idx < NN) part[idx] = excl; excl += v[i]; }
  if (t == 255) bsum[blockIdx.x] = lds[255];
}
__global__ void k_scan2(const int* __restrict__ bsum, int* boff){
  if (threadIdx.x == 0 && blockIdx.x == 0){
    int run = 0;
    for (int i = 0; i < 98; ++i){ boff[i] = run; run += bsum[i]; }
  }
}
__global__ __launch_bounds__(256) void k_scan3(const int* __restrict__ part, const int* __restrict__ boff,
                                               int* rowptr, int* cursor){
  int i = blockIdx.x*256 + threadIdx.x;
  if (i < NN){ int v = part[i] + boff[i >> 10]; rowptr[i] = v; cursor[i] = v; }
  if (i == 0) rowptr[NN] = NN + NE;
}
__global__ __launch_bounds__(256) void k_fill(const int* __restrict__ ei, int* cursor, int* __restrict__ esrc){
  int i = blockIdx.x*256 + threadIdx.x;
  if (i < NE + NN){
    int s, d;
    if (i < NE){ s = ei[i]; d = ei[NE + i]; } else { s = d = i - NE; }
    int slot = atomicAdd(&cursor[d], 1);
    esrc[slot] = s;
  }
}

// ---------------- K3: layer-1 aggregation + bias + ReLU. One wave per dst node ----------------
__global__ __launch_bounds__(256) void k_agg1(const _Float16* __restrict__ xp1,
    const float* __restrict__ asrc, const float* __restrict__ adst,
    const float* __restrict__ b1, const int* __restrict__ rowptr,
    const int* __restrict__ esrc, _Float16* __restrict__ h1)
{
  const int lane = threadIdx.x & 63;
  int n = __builtin_amdgcn_readfirstlane(blockIdx.x*4 + (threadIdx.x >> 6));
  const int h = lane >> 3;                 // head 0..7 (lane covers channels lane*4..+3)
  const float ad = adst[n*8 + h];
  const int jb = rowptr[n], je = rowptr[n+1];
  const h4* xph = (const h4*)xp1;
  float4 acc = make_float4(0,0,0,0);
  float z = 0.f;
  for (int j = jb; j < je; ++j) {
    int s = esrc[j];
    float p = __expf(leaky(asrc[s*8 + h] + ad));
    z += p;
    h4 xv = xph[(size_t)s*64 + lane];
    acc.x += p*(float)xv.x; acc.y += p*(float)xv.y;
    acc.z += p*(float)xv.z; acc.w += p*(float)xv.w;
  }
  const float inv = 1.f / (z + 1e-16f);
  const float4 bb = ((const float4*)b1)[lane];
  h4 o = {(_Float16)fmaxf(acc.x*inv + bb.x, 0.f),
          (_Float16)fmaxf(acc.y*inv + bb.y, 0.f),
          (_Float16)fmaxf(acc.z*inv + bb.z, 0.f),
          (_Float16)fmaxf(acc.w*inv + bb.w, 0.f)};
  ((h4*)h1)[(size_t)n*64 + lane] = o;
}

// ---------------- K4: xp2 = h1 @ W2 via fp16 MFMA + layer-2 attention dots ----------------
// block = 4 waves; wave w: rows r0+w*64 (4 row-tiles), cols 0..47 (3 col-tiles, 40 valid).
__global__ __launch_bounds__(256) void k_gemm2(const _Float16* __restrict__ h1,
    const _Float16* __restrict__ W2t, const float* __restrict__ attS,
    const float* __restrict__ attD, _Float16* __restrict__ xp2,
    float* __restrict__ asrc2, float* __restrict__ adst2)
{
  const int tid  = threadIdx.x;
  const int lane = tid & 63;
  const int w    = tid >> 6;
  const int n = lane & 15, quad = lane >> 4;
  const int r0 = blockIdx.x * 256 + w*64;

  float aSc[3], aDc[3];
  #pragma unroll
  for (int ct = 0; ct < 3; ++ct){
    int col = ct*16 + n;
    aSc[ct] = (col < OC) ? attS[col] : 0.f;
    aDc[ct] = (col < OC) ? attD[col] : 0.f;
  }

  f4v acc[4][3];
  #pragma unroll
  for (int rt = 0; rt < 4; ++rt)
    #pragma unroll
    for (int ct = 0; ct < 3; ++ct) acc[rt][ct] = (f4v){0.f,0.f,0.f,0.f};

  int rr[4];
  #pragma unroll
  for (int rt = 0; rt < 4; ++rt){
    int r = r0 + rt*16 + n;
    rr[rt] = (r < NN) ? r : NN-1;   // stays inside workspace; masked at store
  }

  #pragma unroll
  for (int ks = 0; ks < 8; ++ks){
    h8 b[3];
    #pragma unroll
    for (int ct = 0; ct < 3; ++ct)
      b[ct] = *(const h8*)(W2t + (size_t)(ct*16 + n)*256 + ks*32 + quad*8);
    #pragma unroll
    for (int rt = 0; rt < 4; ++rt){
      h8 a = *(const h8*)(h1 + (size_t)rr[rt]*256 + ks*32 + quad*8);
      #pragma unroll
      for (int ct = 0; ct < 3; ++ct)
        acc[rt][ct] = __builtin_amdgcn_mfma_f32_16x16x32_f16(a, b[ct], acc[rt][ct], 0, 0, 0);
    }
  }

  #pragma unroll
  for (int rt = 0; rt < 4; ++rt){
    #pragma unroll
    for (int reg = 0; reg < 4; ++reg){
      const int row = r0 + rt*16 + quad*4 + reg;
      const bool ok = row < NN;
      float v0 = acc[rt][0][reg], v1 = acc[rt][1][reg], v2 = acc[rt][2][reg];
      float s = v0*aSc[0] + v1*aSc[1] + v2*aSc[2];
      float d = v0*aDc[0] + v1*aDc[1] + v2*aDc[2];
      #pragma unroll
      for (int off = 1; off < 16; off <<= 1){
        s += __shfl_xor(s, off, 64);
        d += __shfl_xor(d, off, 64);
      }
      if (ok){
        _Float16* xr = xp2 + (size_t)row*OC + n;
        xr[0]  = (_Float16)v0;
        xr[16] = (_Float16)v1;
        if (n < 8) xr[32] = (_Float16)v2;
        if (n == 0){ asrc2[row] = s; adst2[row] = d; }
      }
    }
  }
}

// ---------------- K5: layer-2 aggregation + bias + log_softmax. One wave per node ----------------
__global__ __launch_bounds__(256) void k_agg2(const _Float16* __restrict__ xp2,
    const float* __restrict__ asrc2, const float* __restrict__ adst2,
    const float* __restrict__ b2, const int* __restrict__ rowptr,
    const int* __restrict__ esrc, float* __restrict__ out)
{
  const int lane = threadIdx.x & 63;
  int n = __builtin_amdgcn_readfirstlane(blockIdx.x*4 + (threadIdx.x >> 6));
  const float ad = adst2[n];
  const int jb = rowptr[n], je = rowptr[n+1];
  const bool act = lane < OC;
  float acc = 0.f, z = 0.f;
  for (int j = jb; j < je; ++j) {
    int s = esrc[j];
    float p = __expf(leaky(asrc2[s] + ad));
    z += p;
    if (act) acc += p * (float)xp2[(size_t)s*OC + lane];
  }
  float val = act ? (acc/(z + 1e-16f) + b2[lane]) : -INFINITY;
  float m = val;
  #pragma unroll
  for (int off = 32; off > 0; off >>= 1) m = fmaxf(m, __shfl_xor(m, off, 64));
  float e = act ? __expf(val - m) : 0.f;
  float sum = e;
  #pragma unroll
  for (int off = 32; off > 0; off >>= 1) sum += __shfl_xor(sum, off, 64);
  if (act) out[(size_t)n*OC + lane] = val - m - __logf(sum);
}

extern "C" void kernel_launch(void* const* d_in, const int* in_sizes, int n_in,
                              void* d_out, int out_size, void* d_ws, size_t ws_size,
                              hipStream_t stream)
{
  const float* x   = (const float*)d_in[0];
  const int*   ei  = (const int*)  d_in[1];
  const float* W1  = (const float*)d_in[2];
  const float* aS1 = (const float*)d_in[3];
  const float* aD1 = (const float*)d_in[4];
  const float* b1  = (const float*)d_in[5];
  const float* W2  = (const float*)d_in[6];
  const float* aS2 = (const float*)d_in[7];
  const float* aD2 = (const float*)d_in[8];
  const float* b2  = (const float*)d_in[9];
  float* out = (float*)d_out;

  char* wsp = (char*)d_ws;
  size_t off = 0;
  auto alloc = [&](size_t bytes){ void* p = wsp + off; off += (bytes + 255) & ~(size_t)255; return p; };
  _Float16* xp1 = (_Float16*)alloc((size_t)NN*C1*2);   // fp16; reused as xp2 after agg1
  _Float16* h1  = (_Float16*)alloc((size_t)NN*C1*2);   // fp16
  float* as1  = (float*)alloc((size_t)NN*8*4);
  float* ad1  = (float*)alloc((size_t)NN*8*4);
  float* as2  = (float*)alloc((size_t)NN*4);
  float* ad2  = (float*)alloc((size_t)NN*4);
  int* deg    = (int*)alloc((size_t)NN*4);
  int* part   = (int*)alloc((size_t)NN*4);
  int* rowptr = (int*)alloc((size_t)(NN+1)*4);
  int* cursor = (int*)alloc((size_t)NN*4);
  int* bsum   = (int*)alloc(98*4);
  int* boff   = (int*)alloc(98*4);
  int* esrc   = (int*)alloc((size_t)(NN+NE)*4);
  _Float16* W1t = (_Float16*)alloc((size_t)256*128*2);
  _Float16* W2t = (_Float16*)alloc((size_t)48*256*2);
  _Float16* xp2 = xp1;
  (void)ws_size; (void)in_sizes; (void)n_in; (void)out_size;

  k_w1t      <<<128,  256, 0, stream>>>(W1, W1t);
  k_w2t      <<<48,   256, 0, stream>>>(W2, W2t);
  k_gemm1    <<<1563, 256, 0, stream>>>(x, W1t, aS1, aD1, xp1, as1, ad1);
  k_deg_init <<<391,  256, 0, stream>>>(deg);
  k_deg_count<<<3125, 256, 0, stream>>>(ei, deg);
  k_scan1    <<<98,   256, 0, stream>>>(deg, part, bsum);
  k_scan2    <<<1,    64,  0, stream>>>(bsum, boff);
  k_scan3    <<<391,  256, 0, stream>>>(part, boff, rowptr, cursor);
  k_fill     <<<3516, 256, 0, stream>>>(ei, cursor, esrc);
  k_agg1     <<<25000,256, 0, stream>>>(xp1, as1, ad1, b1, rowptr, esrc, h1);
  k_gemm2    <<<391,  256, 0, stream>>>(h1, W2t, aS2, aD2, xp2, as2, ad2);
  k_agg2     <<<25000,256, 0, stream>>>(xp2, as2, ad2, b2, rowptr, esrc, out);
}

// Round 4
// 441.004 us; speedup vs baseline: 1.4366x; 1.0034x over previous
//
#include <hip/hip_runtime.h>
#include <math.h>

#define NN 100000
#define NE 800000
#define C1 256   // HEADS*HID
#define OC 40
#define NEG 0.2f

typedef _Float16 h4 __attribute__((ext_vector_type(4)));
typedef _Float16 h8 __attribute__((ext_vector_type(8)));
typedef float f4v __attribute__((ext_vector_type(4)));

static __device__ __forceinline__ float leaky(float v){ return v > 0.f ? v : NEG*v; }

static __device__ __forceinline__ h8 cvt8(const float4* p){
  float4 a = p[0], b = p[1];
  h8 r = {(_Float16)a.x,(_Float16)a.y,(_Float16)a.z,(_Float16)a.w,
          (_Float16)b.x,(_Float16)b.y,(_Float16)b.z,(_Float16)b.w};
  return r;
}

// ---------------- tiny weight transposes (fp16) ----------------
__global__ __launch_bounds__(256) void k_w1t(const float* __restrict__ W1, _Float16* __restrict__ W1t){
  int k = blockIdx.x;        // 128
  int nb = threadIdx.x;      // 256
  W1t[(size_t)nb*128 + k] = (_Float16)W1[k*256 + nb];
}
__global__ __launch_bounds__(256) void k_w2t(const float* __restrict__ W2, _Float16* __restrict__ W2t){
  int nb = blockIdx.x;       // 48 (pad 40->48 with zeros)
  int k = threadIdx.x;       // 256
  float v = (nb < OC) ? W2[(size_t)k*OC + nb] : 0.f;
  W2t[(size_t)nb*256 + k] = (_Float16)v;
}

// ---------------- K1: xp1 = x @ W1 via fp16 MFMA + fused attention dots ----------------
__global__ __launch_bounds__(256) void k_gemm1(const float* __restrict__ x,
    const _Float16* __restrict__ W1t, const float* __restrict__ attS,
    const float* __restrict__ attD, _Float16* __restrict__ xp1,
    float* __restrict__ asrc, float* __restrict__ adst)
{
  const int tid  = threadIdx.x;
  const int lane = tid & 63;
  const int w    = tid >> 6;
  const int wr = w >> 1, wc = w & 1;
  const int n = lane & 15, quad = lane >> 4;
  const int r0 = blockIdx.x * 64;

  float aSc[8], aDc[8];
  #pragma unroll
  for (int ct = 0; ct < 8; ++ct){
    int col = wc*128 + ct*16 + n;
    aSc[ct] = attS[col]; aDc[ct] = attD[col];
  }

  f4v acc[2][8];
  #pragma unroll
  for (int rt = 0; rt < 2; ++rt)
    #pragma unroll
    for (int ct = 0; ct < 8; ++ct) acc[rt][ct] = (f4v){0.f,0.f,0.f,0.f};

  const int row0 = r0 + wr*32 + n;
  const int ra = (row0      < NN) ? row0      : NN-1;
  const int rb = (row0 + 16 < NN) ? row0 + 16 : NN-1;

  #pragma unroll
  for (int ks = 0; ks < 4; ++ks){
    h8 a0 = cvt8((const float4*)(x + (size_t)ra*128 + ks*32 + quad*8));
    h8 a1 = cvt8((const float4*)(x + (size_t)rb*128 + ks*32 + quad*8));
    #pragma unroll
    for (int ct = 0; ct < 8; ++ct){
      h8 b = *(const h8*)(W1t + (size_t)(wc*128 + ct*16 + n)*128 + ks*32 + quad*8);
      acc[0][ct] = __builtin_amdgcn_mfma_f32_16x16x32_f16(a0, b, acc[0][ct], 0, 0, 0);
      acc[1][ct] = __builtin_amdgcn_mfma_f32_16x16x32_f16(a1, b, acc[1][ct], 0, 0, 0);
    }
  }

  #pragma unroll
  for (int rt = 0; rt < 2; ++rt){
    #pragma unroll
    for (int reg = 0; reg < 4; ++reg){
      const int row = r0 + wr*32 + rt*16 + quad*4 + reg;
      const bool ok = row < NN;
      float v[8];
      #pragma unroll
      for (int ct = 0; ct < 8; ++ct) v[ct] = acc[rt][ct][reg];
      if (ok){
        _Float16* xr = xp1 + (size_t)row*256 + wc*128 + n;
        #pragma unroll
        for (int ct = 0; ct < 8; ++ct) xr[ct*16] = (_Float16)v[ct];
      }
      float s[4], d[4];
      #pragma unroll
      for (int h = 0; h < 4; ++h){
        s[h] = v[2*h]*aSc[2*h] + v[2*h+1]*aSc[2*h+1];
        d[h] = v[2*h]*aDc[2*h] + v[2*h+1]*aDc[2*h+1];
      }
      #pragma unroll
      for (int off = 1; off < 16; off <<= 1){
        #pragma unroll
        for (int h = 0; h < 4; ++h){
          s[h] += __shfl_xor(s[h], off, 64);
          d[h] += __shfl_xor(d[h], off, 64);
        }
      }
      if (ok && n == 0){
        #pragma unroll
        for (int h = 0; h < 4; ++h){
          asrc[row*8 + wc*4 + h] = s[h];
          adst[row*8 + wc*4 + h] = d[h];
        }
      }
    }
  }
}

// ---------------- CSR build (dst-sorted), self-loop slot reserved via deg init = 1 ----------------
__global__ __launch_bounds__(256) void k_deg_init(int* deg){
  int i = blockIdx.x*256 + threadIdx.x;
  if (i < NN) deg[i] = 1;
}
__global__ __launch_bounds__(256) void k_deg_count(const int* __restrict__ ei, int* deg){
  int i = blockIdx.x*256 + threadIdx.x;
  if (i < NE) atomicAdd(&deg[ei[NE + i]], 1);
}
__global__ __launch_bounds__(256) void k_scan1(const int* __restrict__ deg, int* part, int* bsum){
  __shared__ int lds[256];
  const int t = threadIdx.x;
  const int base = blockIdx.x*1024;
  int v[4]; int s = 0;
  #pragma unroll
  for (int i = 0; i < 4; ++i){ int idx = base + t*4 + i; v[i] = (idx < NN) ? deg[idx] : 0; s += v[i]; }
  lds[t] = s; __syncthreads();
  for (int off = 1; off < 256; off <<= 1){
    int xx = (t >= off) ? lds[t-off] : 0;
    __syncthreads();
    lds[t] += xx;
    __syncthreads();
  }
  int excl = lds[t] - s;
  #pragma unroll
  for (int i = 0; i < 4; ++i){ int idx = base + t*4 + i; if (idx < NN) part[idx] = excl; excl += v[i]; }
  if (t == 255) bsum[blockIdx.x] = lds[255];
}
__global__ void k_scan2(const int* __restrict__ bsum, int* boff){
  if (threadIdx.x == 0 && blockIdx.x == 0){
    int run = 0;
    for (int i = 0; i < 98; ++i){ boff[i] = run; run += bsum[i]; }
  }
}
__global__ __launch_bounds__(256) void k_scan3(const int* __restrict__ part, const int* __restrict__ boff,
                                               int* rowptr, int* cursor){
  int i = blockIdx.x*256 + threadIdx.x;
  if (i < NN){ int v = part[i] + boff[i >> 10]; rowptr[i] = v; cursor[i] = v; }
  if (i == 0) rowptr[NN] = NN + NE;
}
__global__ __launch_bounds__(256) void k_fill(const int* __restrict__ ei, int* cursor, int* __restrict__ esrc){
  int i = blockIdx.x*256 + threadIdx.x;
  if (i < NE + NN){
    int s, d;
    if (i < NE){ s = ei[i]; d = ei[NE + i]; } else { s = d = i - NE; }
    int slot = atomicAdd(&cursor[d], 1);
    esrc[slot] = s;
  }
}

// ---------------- K3: layer-1 aggregation, edge-batched (8/batch). One wave per dst node ----------------
// Channel layout: lane covers channels lane*4..+3, head h = lane>>3.
// Batch layout: lane = le*8+lh (le = edge slot 0..7, lh = head).
__global__ __launch_bounds__(256) void k_agg1(const _Float16* __restrict__ xp1,
    const float* __restrict__ asrc, const float* __restrict__ adst,
    const float* __restrict__ b1, const int* __restrict__ rowptr,
    const int* __restrict__ esrc, _Float16* __restrict__ h1)
{
  const int lane = threadIdx.x & 63;
  int n = __builtin_amdgcn_readfirstlane(blockIdx.x*4 + (threadIdx.x >> 6));
  const int h  = lane >> 3;     // channel-layout head
  const int le = lane >> 3;     // batch-layout edge slot (same bits, different role)
  const int lh = lane & 7;      // batch-layout head
  const float adl = adst[n*8 + lh];
  const int jb = rowptr[n], je = rowptr[n+1];
  const h4* xph = (const h4*)xp1;
  float4 acc = make_float4(0,0,0,0);
  float zacc = 0.f;   // per-lane partial z in batch layout (slot le, head lh)

  for (int j0 = jb; j0 < je; j0 += 8) {
    const int cnt = je - j0;    // >= 1; clip to 8 via masking
    int sv = 0;
    if (lane < cnt && lane < 8) sv = esrc[j0 + lane];
    const int se = __shfl(sv, le, 64);
    float pv = 0.f;
    if (le < cnt) pv = __expf(leaky(asrc[se*8 + lh] + adl));
    zacc += pv;
    #pragma unroll
    for (int e = 0; e < 8; ++e) {
      const float p = __shfl(pv, e*8 + h, 64);   // bpermute
      const int   s = __shfl(sv, e, 64);          // readlane -> sgpr base
      h4 xv = xph[(size_t)s*64 + lane];           // coalesced 512B wave row load
      acc.x += p*(float)xv.x; acc.y += p*(float)xv.y;
      acc.z += p*(float)xv.z; acc.w += p*(float)xv.w;
    }
  }
  // z: reduce over edge slots (lanes sharing lh), then move to channel layout
  zacc += __shfl_xor(zacc, 8, 64);
  zacc += __shfl_xor(zacc, 16, 64);
  zacc += __shfl_xor(zacc, 32, 64);
  const float z = __shfl(zacc, h, 64);   // lane h holds z for head h
  const float inv = 1.f / (z + 1e-16f);
  const float4 bb = ((const float4*)b1)[lane];
  h4 o = {(_Float16)fmaxf(acc.x*inv + bb.x, 0.f),
          (_Float16)fmaxf(acc.y*inv + bb.y, 0.f),
          (_Float16)fmaxf(acc.z*inv + bb.z, 0.f),
          (_Float16)fmaxf(acc.w*inv + bb.w, 0.f)};
  ((h4*)h1)[(size_t)n*64 + lane] = o;
}

// ---------------- K4: xp2 = h1 @ W2 via fp16 MFMA + layer-2 attention dots ----------------
__global__ __launch_bounds__(256) void k_gemm2(const _Float16* __restrict__ h1,
    const _Float16* __restrict__ W2t, const float* __restrict__ attS,
    const float* __restrict__ attD, _Float16* __restrict__ xp2,
    float* __restrict__ asrc2, float* __restrict__ adst2)
{
  const int tid  = threadIdx.x;
  const int lane = tid & 63;
  const int w    = tid >> 6;
  const int n = lane & 15, quad = lane >> 4;
  const int r0 = blockIdx.x * 256 + w*64;

  float aSc[3], aDc[3];
  #pragma unroll
  for (int ct = 0; ct < 3; ++ct){
    int col = ct*16 + n;
    aSc[ct] = (col < OC) ? attS[col] : 0.f;
    aDc[ct] = (col < OC) ? attD[col] : 0.f;
  }

  f4v acc[4][3];
  #pragma unroll
  for (int rt = 0; rt < 4; ++rt)
    #pragma unroll
    for (int ct = 0; ct < 3; ++ct) acc[rt][ct] = (f4v){0.f,0.f,0.f,0.f};

  int rr[4];
  #pragma unroll
  for (int rt = 0; rt < 4; ++rt){
    int r = r0 + rt*16 + n;
    rr[rt] = (r < NN) ? r : NN-1;
  }

  #pragma unroll
  for (int ks = 0; ks < 8; ++ks){
    h8 b[3];
    #pragma unroll
    for (int ct = 0; ct < 3; ++ct)
      b[ct] = *(const h8*)(W2t + (size_t)(ct*16 + n)*256 + ks*32 + quad*8);
    #pragma unroll
    for (int rt = 0; rt < 4; ++rt){
      h8 a = *(const h8*)(h1 + (size_t)rr[rt]*256 + ks*32 + quad*8);
      #pragma unroll
      for (int ct = 0; ct < 3; ++ct)
        acc[rt][ct] = __builtin_amdgcn_mfma_f32_16x16x32_f16(a, b[ct], acc[rt][ct], 0, 0, 0);
    }
  }

  #pragma unroll
  for (int rt = 0; rt < 4; ++rt){
    #pragma unroll
    for (int reg = 0; reg < 4; ++reg){
      const int row = r0 + rt*16 + quad*4 + reg;
      const bool ok = row < NN;
      float v0 = acc[rt][0][reg], v1 = acc[rt][1][reg], v2 = acc[rt][2][reg];
      float s = v0*aSc[0] + v1*aSc[1] + v2*aSc[2];
      float d = v0*aDc[0] + v1*aDc[1] + v2*aDc[2];
      #pragma unroll
      for (int off = 1; off < 16; off <<= 1){
        s += __shfl_xor(s, off, 64);
        d += __shfl_xor(d, off, 64);
      }
      if (ok){
        _Float16* xr = xp2 + (size_t)row*OC + n;
        xr[0]  = (_Float16)v0;
        xr[16] = (_Float16)v1;
        if (n < 8) xr[32] = (_Float16)v2;
        if (n == 0){ asrc2[row] = s; adst2[row] = d; }
      }
    }
  }
}

// ---------------- K5: layer-2 aggregation, edge-batched (16/batch). One wave per node ----------------
__global__ __launch_bounds__(256) void k_agg2(const _Float16* __restrict__ xp2,
    const float* __restrict__ asrc2, const float* __restrict__ adst2,
    const float* __restrict__ b2, const int* __restrict__ rowptr,
    const int* __restrict__ esrc, float* __restrict__ out)
{
  const int lane = threadIdx.x & 63;
  int n = __builtin_amdgcn_readfirstlane(blockIdx.x*4 + (threadIdx.x >> 6));
  const float ad = adst2[n];
  const int jb = rowptr[n], je = rowptr[n+1];
  const bool act = lane < OC;
  float acc = 0.f, zacc = 0.f;

  for (int j0 = jb; j0 < je; j0 += 16) {
    const int cnt = je - j0;
    int sv = 0;
    if (lane < cnt && lane < 16) sv = esrc[j0 + lane];
    float pv = 0.f;
    if (lane < cnt && lane < 16) pv = __expf(leaky(asrc2[sv] + ad));
    zacc += pv;
    #pragma unroll
    for (int e = 0; e < 16; ++e) {
      const float p = __shfl(pv, e, 64);          // readlane -> sgpr
      const int   s = __shfl(sv, e, 64);          // readlane -> sgpr base
      if (act) acc += p * (float)xp2[(size_t)s*OC + lane];  // coalesced 80B row load
    }
  }
  // z: full wave reduce (lanes >=16 contribute 0)
  #pragma unroll
  for (int off = 1; off < 64; off <<= 1) zacc += __shfl_xor(zacc, off, 64);

  float val = act ? (acc/(zacc + 1e-16f) + b2[lane]) : -INFINITY;
  float m = val;
  #pragma unroll
  for (int off = 32; off > 0; off >>= 1) m = fmaxf(m, __shfl_xor(m, off, 64));
  float e = act ? __expf(val - m) : 0.f;
  float sum = e;
  #pragma unroll
  for (int off = 32; off > 0; off >>= 1) sum += __shfl_xor(sum, off, 64);
  if (act) out[(size_t)n*OC + lane] = val - m - __logf(sum);
}

extern "C" void kernel_launch(void* const* d_in, const int* in_sizes, int n_in,
                              void* d_out, int out_size, void* d_ws, size_t ws_size,
                              hipStream_t stream)
{
  const float* x   = (const float*)d_in[0];
  const int*   ei  = (const int*)  d_in[1];
  const float* W1  = (const float*)d_in[2];
  const float* aS1 = (const float*)d_in[3];
  const float* aD1 = (const float*)d_in[4];
  const float* b1  = (const float*)d_in[5];
  const float* W2  = (const float*)d_in[6];
  const float* aS2 = (const float*)d_in[7];
  const float* aD2 = (const float*)d_in[8];
  const float* b2  = (const float*)d_in[9];
  float* out = (float*)d_out;

  char* wsp = (char*)d_ws;
  size_t off = 0;
  auto alloc = [&](size_t bytes){ void* p = wsp + off; off += (bytes + 255) & ~(size_t)255; return p; };
  _Float16* xp1 = (_Float16*)alloc((size_t)NN*C1*2);   // fp16; reused as xp2 after agg1
  _Float16* h1  = (_Float16*)alloc((size_t)NN*C1*2);   // fp16
  float* as1  = (float*)alloc((size_t)NN*8*4);
  float* ad1  = (float*)alloc((size_t)NN*8*4);
  float* as2  = (float*)alloc((size_t)NN*4);
  float* ad2  = (float*)alloc((size_t)NN*4);
  int* deg    = (int*)alloc((size_t)NN*4);
  int* part   = (int*)alloc((size_t)NN*4);
  int* rowptr = (int*)alloc((size_t)(NN+1)*4);
  int* cursor = (int*)alloc((size_t)NN*4);
  int* bsum   = (int*)alloc(98*4);
  int* boff   = (int*)alloc(98*4);
  int* esrc   = (int*)alloc((size_t)(NN+NE)*4);
  _Float16* W1t = (_Float16*)alloc((size_t)256*128*2);
  _Float16* W2t = (_Float16*)alloc((size_t)48*256*2);
  _Float16* xp2 = xp1;
  (void)ws_size; (void)in_sizes; (void)n_in; (void)out_size;

  k_w1t      <<<128,  256, 0, stream>>>(W1, W1t);
  k_w2t      <<<48,   256, 0, stream>>>(W2, W2t);
  k_gemm1    <<<1563, 256, 0, stream>>>(x, W1t, aS1, aD1, xp1, as1, ad1);
  k_deg_init <<<391,  256, 0, stream>>>(deg);
  k_deg_count<<<3125, 256, 0, stream>>>(ei, deg);
  k_scan1    <<<98,   256, 0, stream>>>(deg, part, bsum);
  k_scan2    <<<1,    64,  0, stream>>>(bsum, boff);
  k_scan3    <<<391,  256, 0, stream>>>(part, boff, rowptr, cursor);
  k_fill     <<<3516, 256, 0, stream>>>(ei, cursor, esrc);
  k_agg1     <<<25000,256, 0, stream>>>(xp1, as1, ad1, b1, rowptr, esrc, h1);
  k_gemm2    <<<391,  256, 0, stream>>>(h1, W2t, aS2, aD2, xp2, as2, ad2);
  k_agg2     <<<25000,256, 0, stream>>>(xp2, as2, ad2, b2, rowptr, esrc, out);
}

// Round 5
// 430.025 us; speedup vs baseline: 1.4733x; 1.0255x over previous
//
#include <hip/hip_runtime.h>
#include <math.h>

#define NN 100000
#define NE 800000
#define C1 256   // HEADS*HID
#define OC 40
#define XPAD 64  // padded xp2 row stride (fp16) = 128 B = 1 cacheline
#define NEG 0.2f

typedef _Float16 h4 __attribute__((ext_vector_type(4)));
typedef _Float16 h8 __attribute__((ext_vector_type(8)));
typedef float f4v __attribute__((ext_vector_type(4)));

static __device__ __forceinline__ float leaky(float v){ return v > 0.f ? v : NEG*v; }

static __device__ __forceinline__ h8 cvt8(const float4* p){
  float4 a = p[0], b = p[1];
  h8 r = {(_Float16)a.x,(_Float16)a.y,(_Float16)a.z,(_Float16)a.w,
          (_Float16)b.x,(_Float16)b.y,(_Float16)b.z,(_Float16)b.w};
  return r;
}

// ---------------- tiny weight transposes (fp16) ----------------
__global__ __launch_bounds__(256) void k_w1t(const float* __restrict__ W1, _Float16* __restrict__ W1t){
  int k = blockIdx.x;        // 128
  int nb = threadIdx.x;      // 256
  W1t[(size_t)nb*128 + k] = (_Float16)W1[k*256 + nb];
}
__global__ __launch_bounds__(256) void k_w2t(const float* __restrict__ W2, _Float16* __restrict__ W2t){
  int nb = blockIdx.x;       // 48 (pad 40->48 with zeros)
  int k = threadIdx.x;       // 256
  float v = (nb < OC) ? W2[(size_t)k*OC + nb] : 0.f;
  W2t[(size_t)nb*256 + k] = (_Float16)v;
}

// ---------------- K1: xp1 = x @ W1 via fp16 MFMA + fused attention dots ----------------
__global__ __launch_bounds__(256) void k_gemm1(const float* __restrict__ x,
    const _Float16* __restrict__ W1t, const float* __restrict__ attS,
    const float* __restrict__ attD, _Float16* __restrict__ xp1,
    float* __restrict__ asrc, float* __restrict__ adst)
{
  const int tid  = threadIdx.x;
  const int lane = tid & 63;
  const int w    = tid >> 6;
  const int wr = w >> 1, wc = w & 1;
  const int n = lane & 15, quad = lane >> 4;
  const int r0 = blockIdx.x * 64;

  float aSc[8], aDc[8];
  #pragma unroll
  for (int ct = 0; ct < 8; ++ct){
    int col = wc*128 + ct*16 + n;
    aSc[ct] = attS[col]; aDc[ct] = attD[col];
  }

  f4v acc[2][8];
  #pragma unroll
  for (int rt = 0; rt < 2; ++rt)
    #pragma unroll
    for (int ct = 0; ct < 8; ++ct) acc[rt][ct] = (f4v){0.f,0.f,0.f,0.f};

  const int row0 = r0 + wr*32 + n;
  const int ra = (row0      < NN) ? row0      : NN-1;
  const int rb = (row0 + 16 < NN) ? row0 + 16 : NN-1;

  #pragma unroll
  for (int ks = 0; ks < 4; ++ks){
    h8 a0 = cvt8((const float4*)(x + (size_t)ra*128 + ks*32 + quad*8));
    h8 a1 = cvt8((const float4*)(x + (size_t)rb*128 + ks*32 + quad*8));
    #pragma unroll
    for (int ct = 0; ct < 8; ++ct){
      h8 b = *(const h8*)(W1t + (size_t)(wc*128 + ct*16 + n)*128 + ks*32 + quad*8);
      acc[0][ct] = __builtin_amdgcn_mfma_f32_16x16x32_f16(a0, b, acc[0][ct], 0, 0, 0);
      acc[1][ct] = __builtin_amdgcn_mfma_f32_16x16x32_f16(a1, b, acc[1][ct], 0, 0, 0);
    }
  }

  #pragma unroll
  for (int rt = 0; rt < 2; ++rt){
    #pragma unroll
    for (int reg = 0; reg < 4; ++reg){
      const int row = r0 + wr*32 + rt*16 + quad*4 + reg;
      const bool ok = row < NN;
      float v[8];
      #pragma unroll
      for (int ct = 0; ct < 8; ++ct) v[ct] = acc[rt][ct][reg];
      if (ok){
        _Float16* xr = xp1 + (size_t)row*256 + wc*128 + n;
        #pragma unroll
        for (int ct = 0; ct < 8; ++ct) xr[ct*16] = (_Float16)v[ct];
      }
      float s[4], d[4];
      #pragma unroll
      for (int h = 0; h < 4; ++h){
        s[h] = v[2*h]*aSc[2*h] + v[2*h+1]*aSc[2*h+1];
        d[h] = v[2*h]*aDc[2*h] + v[2*h+1]*aDc[2*h+1];
      }
      #pragma unroll
      for (int off = 1; off < 16; off <<= 1){
        #pragma unroll
        for (int h = 0; h < 4; ++h){
          s[h] += __shfl_xor(s[h], off, 64);
          d[h] += __shfl_xor(d[h], off, 64);
        }
      }
      if (ok && n == 0){
        #pragma unroll
        for (int h = 0; h < 4; ++h){
          asrc[row*8 + wc*4 + h] = s[h];
          adst[row*8 + wc*4 + h] = d[h];
        }
      }
    }
  }
}

// ---------------- CSR build (dst-sorted), self-loop slot reserved via deg init = 1 ----------------
__global__ __launch_bounds__(256) void k_deg_init(int* deg){
  int i = blockIdx.x*256 + threadIdx.x;
  if (i < NN) deg[i] = 1;
}
__global__ __launch_bounds__(256) void k_deg_count(const int* __restrict__ ei, int* deg){
  int i = blockIdx.x*256 + threadIdx.x;
  if (i < NE) atomicAdd(&deg[ei[NE + i]], 1);
}
__global__ __launch_bounds__(256) void k_scan1(const int* __restrict__ deg, int* part, int* bsum){
  __shared__ int lds[256];
  const int t = threadIdx.x;
  const int base = blockIdx.x*1024;
  int v[4]; int s = 0;
  #pragma unroll
  for (int i = 0; i < 4; ++i){ int idx = base + t*4 + i; v[i] = (idx < NN) ? deg[idx] : 0; s += v[i]; }
  lds[t] = s; __syncthreads();
  for (int off = 1; off < 256; off <<= 1){
    int xx = (t >= off) ? lds[t-off] : 0;
    __syncthreads();
    lds[t] += xx;
    __syncthreads();
  }
  int excl = lds[t] - s;
  #pragma unroll
  for (int i = 0; i < 4; ++i){ int idx = base + t*4 + i; if (idx < NN) part[idx] = excl; excl += v[i]; }
  if (t == 255) bsum[blockIdx.x] = lds[255];
}
__global__ void k_scan2(const int* __restrict__ bsum, int* boff){
  if (threadIdx.x == 0 && blockIdx.x == 0){
    int run = 0;
    for (int i = 0; i < 98; ++i){ boff[i] = run; run += bsum[i]; }
  }
}
__global__ __launch_bounds__(256) void k_scan3(const int* __restrict__ part, const int* __restrict__ boff,
                                               int* rowptr, int* cursor){
  int i = blockIdx.x*256 + threadIdx.x;
  if (i < NN){ int v = part[i] + boff[i >> 10]; rowptr[i] = v; cursor[i] = v; }
  if (i == 0) rowptr[NN] = NN + NE;
}
__global__ __launch_bounds__(256) void k_fill(const int* __restrict__ ei, int* cursor, int* __restrict__ esrc){
  int i = blockIdx.x*256 + threadIdx.x;
  if (i < NE + NN){
    int s, d;
    if (i < NE){ s = ei[i]; d = ei[NE + i]; } else { s = d = i - NE; }
    int slot = atomicAdd(&cursor[d], 1);
    esrc[slot] = s;
  }
}

// ---------------- K3: layer-1 aggregation, edge-batched (8/batch, uniform break). One wave per dst ----------------
__global__ __launch_bounds__(256) void k_agg1(const _Float16* __restrict__ xp1,
    const float* __restrict__ asrc, const float* __restrict__ adst,
    const float* __restrict__ b1, const int* __restrict__ rowptr,
    const int* __restrict__ esrc, _Float16* __restrict__ h1)
{
  const int lane = threadIdx.x & 63;
  int n = __builtin_amdgcn_readfirstlane(blockIdx.x*4 + (threadIdx.x >> 6));
  const int h  = lane >> 3;     // channel-layout head
  const int le = lane >> 3;     // batch-layout edge slot
  const int lh = lane & 7;      // batch-layout head
  const float adl = adst[n*8 + lh];
  const int jb = rowptr[n], je = rowptr[n+1];
  const h4* xph = (const h4*)xp1;
  float4 acc = make_float4(0,0,0,0);
  float zacc = 0.f;

  for (int j0 = jb; j0 < je; j0 += 8) {
    const int cnt = je - j0;    // wave-uniform (SGPR) -> scalar branches below
    int sv = 0;
    if (lane < cnt && lane < 8) sv = esrc[j0 + lane];
    const int se = __shfl(sv, le, 64);
    float pv = 0.f;
    if (le < cnt) pv = __expf(leaky(asrc[se*8 + lh] + adl));
    zacc += pv;
    #pragma unroll
    for (int e = 0; e < 8; ++e) {
      if (e >= cnt) break;                        // uniform early-exit: skip empty slots
      const float p = __shfl(pv, e*8 + h, 64);
      const int   s = __shfl(sv, e, 64);
      h4 xv = xph[(size_t)s*64 + lane];           // 512B coalesced row (4 aligned lines)
      acc.x += p*(float)xv.x; acc.y += p*(float)xv.y;
      acc.z += p*(float)xv.z; acc.w += p*(float)xv.w;
    }
  }
  zacc += __shfl_xor(zacc, 8, 64);
  zacc += __shfl_xor(zacc, 16, 64);
  zacc += __shfl_xor(zacc, 32, 64);
  const float z = __shfl(zacc, h, 64);
  const float inv = 1.f / (z + 1e-16f);
  const float4 bb = ((const float4*)b1)[lane];
  h4 o = {(_Float16)fmaxf(acc.x*inv + bb.x, 0.f),
          (_Float16)fmaxf(acc.y*inv + bb.y, 0.f),
          (_Float16)fmaxf(acc.z*inv + bb.z, 0.f),
          (_Float16)fmaxf(acc.w*inv + bb.w, 0.f)};
  ((h4*)h1)[(size_t)n*64 + lane] = o;
}

// ---------------- K4: xp2 = h1 @ W2 via fp16 MFMA + layer-2 attention dots ----------------
// xp2 row stride = XPAD(64) fp16 = 128 B: each agg2 gather touches exactly one cacheline.
__global__ __launch_bounds__(256) void k_gemm2(const _Float16* __restrict__ h1,
    const _Float16* __restrict__ W2t, const float* __restrict__ attS,
    const float* __restrict__ attD, _Float16* __restrict__ xp2,
    float* __restrict__ asrc2, float* __restrict__ adst2)
{
  const int tid  = threadIdx.x;
  const int lane = tid & 63;
  const int w    = tid >> 6;
  const int n = lane & 15, quad = lane >> 4;
  const int r0 = blockIdx.x * 256 + w*64;

  float aSc[3], aDc[3];
  #pragma unroll
  for (int ct = 0; ct < 3; ++ct){
    int col = ct*16 + n;
    aSc[ct] = (col < OC) ? attS[col] : 0.f;
    aDc[ct] = (col < OC) ? attD[col] : 0.f;
  }

  f4v acc[4][3];
  #pragma unroll
  for (int rt = 0; rt < 4; ++rt)
    #pragma unroll
    for (int ct = 0; ct < 3; ++ct) acc[rt][ct] = (f4v){0.f,0.f,0.f,0.f};

  int rr[4];
  #pragma unroll
  for (int rt = 0; rt < 4; ++rt){
    int r = r0 + rt*16 + n;
    rr[rt] = (r < NN) ? r : NN-1;
  }

  #pragma unroll
  for (int ks = 0; ks < 8; ++ks){
    h8 b[3];
    #pragma unroll
    for (int ct = 0; ct < 3; ++ct)
      b[ct] = *(const h8*)(W2t + (size_t)(ct*16 + n)*256 + ks*32 + quad*8);
    #pragma unroll
    for (int rt = 0; rt < 4; ++rt){
      h8 a = *(const h8*)(h1 + (size_t)rr[rt]*256 + ks*32 + quad*8);
      #pragma unroll
      for (int ct = 0; ct < 3; ++ct)
        acc[rt][ct] = __builtin_amdgcn_mfma_f32_16x16x32_f16(a, b[ct], acc[rt][ct], 0, 0, 0);
    }
  }

  #pragma unroll
  for (int rt = 0; rt < 4; ++rt){
    #pragma unroll
    for (int reg = 0; reg < 4; ++reg){
      const int row = r0 + rt*16 + quad*4 + reg;
      const bool ok = row < NN;
      float v0 = acc[rt][0][reg], v1 = acc[rt][1][reg], v2 = acc[rt][2][reg];
      float s = v0*aSc[0] + v1*aSc[1] + v2*aSc[2];
      float d = v0*aDc[0] + v1*aDc[1] + v2*aDc[2];
      #pragma unroll
      for (int off = 1; off < 16; off <<= 1){
        s += __shfl_xor(s, off, 64);
        d += __shfl_xor(d, off, 64);
      }
      if (ok){
        _Float16* xr = xp2 + (size_t)row*XPAD + n;
        xr[0]  = (_Float16)v0;
        xr[16] = (_Float16)v1;
        if (n < 8) xr[32] = (_Float16)v2;
        if (n == 0){ asrc2[row] = s; adst2[row] = d; }
      }
    }
  }
}

// ---------------- K5: layer-2 aggregation, edge-batched (16/batch, uniform break). One wave per node ----------------
__global__ __launch_bounds__(256) void k_agg2(const _Float16* __restrict__ xp2,
    const float* __restrict__ asrc2, const float* __restrict__ adst2,
    const float* __restrict__ b2, const int* __restrict__ rowptr,
    const int* __restrict__ esrc, float* __restrict__ out)
{
  const int lane = threadIdx.x & 63;
  int n = __builtin_amdgcn_readfirstlane(blockIdx.x*4 + (threadIdx.x >> 6));
  const float ad = adst2[n];
  const int jb = rowptr[n], je = rowptr[n+1];
  const bool act = lane < OC;
  float acc = 0.f, zacc = 0.f;

  for (int j0 = jb; j0 < je; j0 += 16) {
    const int cnt = je - j0;    // wave-uniform
    int sv = 0;
    if (lane < cnt && lane < 16) sv = esrc[j0 + lane];
    float pv = 0.f;
    if (lane < cnt && lane < 16) pv = __expf(leaky(asrc2[sv] + ad));
    zacc += pv;
    #pragma unroll
    for (int e = 0; e < 16; ++e) {
      if (e >= cnt) break;                        // uniform early-exit
      const float p = __shfl(pv, e, 64);
      const int   s = __shfl(sv, e, 64);
      if (act) acc += p * (float)xp2[(size_t)s*XPAD + lane];  // one 128B line per row
    }
  }
  #pragma unroll
  for (int off = 1; off < 64; off <<= 1) zacc += __shfl_xor(zacc, off, 64);

  float val = act ? (acc/(zacc + 1e-16f) + b2[lane]) : -INFINITY;
  float m = val;
  #pragma unroll
  for (int off = 32; off > 0; off >>= 1) m = fmaxf(m, __shfl_xor(m, off, 64));
  float e = act ? __expf(val - m) : 0.f;
  float sum = e;
  #pragma unroll
  for (int off = 32; off > 0; off >>= 1) sum += __shfl_xor(sum, off, 64);
  if (act) out[(size_t)n*OC + lane] = val - m - __logf(sum);
}

extern "C" void kernel_launch(void* const* d_in, const int* in_sizes, int n_in,
                              void* d_out, int out_size, void* d_ws, size_t ws_size,
                              hipStream_t stream)
{
  const float* x   = (const float*)d_in[0];
  const int*   ei  = (const int*)  d_in[1];
  const float* W1  = (const float*)d_in[2];
  const float* aS1 = (const float*)d_in[3];
  const float* aD1 = (const float*)d_in[4];
  const float* b1  = (const float*)d_in[5];
  const float* W2  = (const float*)d_in[6];
  const float* aS2 = (const float*)d_in[7];
  const float* aD2 = (const float*)d_in[8];
  const float* b2  = (const float*)d_in[9];
  float* out = (float*)d_out;

  char* wsp = (char*)d_ws;
  size_t off = 0;
  auto alloc = [&](size_t bytes){ void* p = wsp + off; off += (bytes + 255) & ~(size_t)255; return p; };
  _Float16* xp1 = (_Float16*)alloc((size_t)NN*C1*2);   // fp16; reused as xp2 (stride XPAD) after agg1
  _Float16* h1  = (_Float16*)alloc((size_t)NN*C1*2);   // fp16
  float* as1  = (float*)alloc((size_t)NN*8*4);
  float* ad1  = (float*)alloc((size_t)NN*8*4);
  float* as2  = (float*)alloc((size_t)NN*4);
  float* ad2  = (float*)alloc((size_t)NN*4);
  int* deg    = (int*)alloc((size_t)NN*4);
  int* part   = (int*)alloc((size_t)NN*4);
  int* rowptr = (int*)alloc((size_t)(NN+1)*4);
  int* cursor = (int*)alloc((size_t)NN*4);
  int* bsum   = (int*)alloc(98*4);
  int* boff   = (int*)alloc(98*4);
  int* esrc   = (int*)alloc((size_t)(NN+NE)*4);
  _Float16* W1t = (_Float16*)alloc((size_t)256*128*2);
  _Float16* W2t = (_Float16*)alloc((size_t)48*256*2);
  _Float16* xp2 = xp1;   // 100k*64*2 = 12.8 MB < 51.2 MB, 128B-aligned rows
  (void)ws_size; (void)in_sizes; (void)n_in; (void)out_size;

  k_w1t      <<<128,  256, 0, stream>>>(W1, W1t);
  k_w2t      <<<48,   256, 0, stream>>>(W2, W2t);
  k_gemm1    <<<1563, 256, 0, stream>>>(x, W1t, aS1, aD1, xp1, as1, ad1);
  k_deg_init <<<391,  256, 0, stream>>>(deg);
  k_deg_count<<<3125, 256, 0, stream>>>(ei, deg);
  k_scan1    <<<98,   256, 0, stream>>>(deg, part, bsum);
  k_scan2    <<<1,    64,  0, stream>>>(bsum, boff);
  k_scan3    <<<391,  256, 0, stream>>>(part, boff, rowptr, cursor);
  k_fill     <<<3516, 256, 0, stream>>>(ei, cursor, esrc);
  k_agg1     <<<25000,256, 0, stream>>>(xp1, as1, ad1, b1, rowptr, esrc, h1);
  k_gemm2    <<<391,  256, 0, stream>>>(h1, W2t, aS2, aD2, xp2, as2, ad2);
  k_agg2     <<<25000,256, 0, stream>>>(xp2, as2, ad2, b2, rowptr, esrc, out);
}

// Round 6
// 419.511 us; speedup vs baseline: 1.5102x; 1.0251x over previous
//
#include <hip/hip_runtime.h>
#include <math.h>

#define NN 100000
#define NE 800000
#define C1 256   // HEADS*HID
#define OC 40
#define XPAD 64  // padded xp2 row stride (fp16) = 128 B = 1 cacheline
#define NEG 0.2f

typedef _Float16 h4 __attribute__((ext_vector_type(4)));
typedef _Float16 h8 __attribute__((ext_vector_type(8)));
typedef float f4v __attribute__((ext_vector_type(4)));
typedef float f2v __attribute__((ext_vector_type(2)));

static __device__ __forceinline__ float leaky(float v){ return v > 0.f ? v : NEG*v; }

static __device__ __forceinline__ h8 cvt8(const float4* p){
  float4 a = p[0], b = p[1];
  h8 r = {(_Float16)a.x,(_Float16)a.y,(_Float16)a.z,(_Float16)a.w,
          (_Float16)b.x,(_Float16)b.y,(_Float16)b.z,(_Float16)b.w};
  return r;
}

// fp8 e4m3 (OCP on gfx950) scalar encode: byte in low 8 bits
static __device__ __forceinline__ unsigned char enc_fp8(float v){
  return (unsigned char)(__builtin_amdgcn_cvt_pk_fp8_f32(v, v, 0, false) & 0xff);
}

// ---------------- tiny weight transposes (fp16) ----------------
__global__ __launch_bounds__(256) void k_w1t(const float* __restrict__ W1, _Float16* __restrict__ W1t){
  int k = blockIdx.x;        // 128
  int nb = threadIdx.x;      // 256
  W1t[(size_t)nb*128 + k] = (_Float16)W1[k*256 + nb];
}
__global__ __launch_bounds__(256) void k_w2t(const float* __restrict__ W2, _Float16* __restrict__ W2t){
  int nb = blockIdx.x;       // 48 (pad 40->48 with zeros)
  int k = threadIdx.x;       // 256
  float v = (nb < OC) ? W2[(size_t)k*OC + nb] : 0.f;
  W2t[(size_t)nb*256 + k] = (_Float16)v;
}

// ---------------- K1: xp1 = x @ W1 via fp16 MFMA -> fp8 store + fused attention dots ----------------
__global__ __launch_bounds__(256) void k_gemm1(const float* __restrict__ x,
    const _Float16* __restrict__ W1t, const float* __restrict__ attS,
    const float* __restrict__ attD, unsigned char* __restrict__ xp1,
    float* __restrict__ asrc, float* __restrict__ adst)
{
  const int tid  = threadIdx.x;
  const int lane = tid & 63;
  const int w    = tid >> 6;
  const int wr = w >> 1, wc = w & 1;
  const int n = lane & 15, quad = lane >> 4;
  const int r0 = blockIdx.x * 64;

  float aSc[8], aDc[8];
  #pragma unroll
  for (int ct = 0; ct < 8; ++ct){
    int col = wc*128 + ct*16 + n;
    aSc[ct] = attS[col]; aDc[ct] = attD[col];
  }

  f4v acc[2][8];
  #pragma unroll
  for (int rt = 0; rt < 2; ++rt)
    #pragma unroll
    for (int ct = 0; ct < 8; ++ct) acc[rt][ct] = (f4v){0.f,0.f,0.f,0.f};

  const int row0 = r0 + wr*32 + n;
  const int ra = (row0      < NN) ? row0      : NN-1;
  const int rb = (row0 + 16 < NN) ? row0 + 16 : NN-1;

  #pragma unroll
  for (int ks = 0; ks < 4; ++ks){
    h8 a0 = cvt8((const float4*)(x + (size_t)ra*128 + ks*32 + quad*8));
    h8 a1 = cvt8((const float4*)(x + (size_t)rb*128 + ks*32 + quad*8));
    #pragma unroll
    for (int ct = 0; ct < 8; ++ct){
      h8 b = *(const h8*)(W1t + (size_t)(wc*128 + ct*16 + n)*128 + ks*32 + quad*8);
      acc[0][ct] = __builtin_amdgcn_mfma_f32_16x16x32_f16(a0, b, acc[0][ct], 0, 0, 0);
      acc[1][ct] = __builtin_amdgcn_mfma_f32_16x16x32_f16(a1, b, acc[1][ct], 0, 0, 0);
    }
  }

  #pragma unroll
  for (int rt = 0; rt < 2; ++rt){
    #pragma unroll
    for (int reg = 0; reg < 4; ++reg){
      const int row = r0 + wr*32 + rt*16 + quad*4 + reg;
      const bool ok = row < NN;
      float v[8];
      #pragma unroll
      for (int ct = 0; ct < 8; ++ct) v[ct] = acc[rt][ct][reg];
      if (ok){
        unsigned char* xr = xp1 + (size_t)row*256 + wc*128 + n;
        #pragma unroll
        for (int ct = 0; ct < 8; ++ct) xr[ct*16] = enc_fp8(v[ct]);
      }
      float s[4], d[4];
      #pragma unroll
      for (int h = 0; h < 4; ++h){
        s[h] = v[2*h]*aSc[2*h] + v[2*h+1]*aSc[2*h+1];
        d[h] = v[2*h]*aDc[2*h] + v[2*h+1]*aDc[2*h+1];
      }
      #pragma unroll
      for (int off = 1; off < 16; off <<= 1){
        #pragma unroll
        for (int h = 0; h < 4; ++h){
          s[h] += __shfl_xor(s[h], off, 64);
          d[h] += __shfl_xor(d[h], off, 64);
        }
      }
      if (ok && n == 0){
        #pragma unroll
        for (int h = 0; h < 4; ++h){
          asrc[row*8 + wc*4 + h] = s[h];
          adst[row*8 + wc*4 + h] = d[h];
        }
      }
    }
  }
}

// ---------------- CSR build (dst-sorted), self-loop slot reserved via deg init = 1 ----------------
__global__ __launch_bounds__(256) void k_deg_init(int* deg){
  int i = blockIdx.x*256 + threadIdx.x;
  if (i < NN) deg[i] = 1;
}
__global__ __launch_bounds__(256) void k_deg_count(const int* __restrict__ ei, int* deg){
  int i = blockIdx.x*256 + threadIdx.x;
  if (i < NE) atomicAdd(&deg[ei[NE + i]], 1);
}
__global__ __launch_bounds__(256) void k_scan1(const int* __restrict__ deg, int* part, int* bsum){
  __shared__ int lds[256];
  const int t = threadIdx.x;
  const int base = blockIdx.x*1024;
  int v[4]; int s = 0;
  #pragma unroll
  for (int i = 0; i < 4; ++i){ int idx = base + t*4 + i; v[i] = (idx < NN) ? deg[idx] : 0; s += v[i]; }
  lds[t] = s; __syncthreads();
  for (int off = 1; off < 256; off <<= 1){
    int xx = (t >= off) ? lds[t-off] : 0;
    __syncthreads();
    lds[t] += xx;
    __syncthreads();
  }
  int excl = lds[t] - s;
  #pragma unroll
  for (int i = 0; i < 4; ++i){ int idx = base + t*4 + i; if (idx < NN) part[idx] = excl; excl += v[i]; }
  if (t == 255) bsum[blockIdx.x] = lds[255];
}
__global__ void k_scan2(const int* __restrict__ bsum, int* boff){
  if (threadIdx.x == 0 && blockIdx.x == 0){
    int run = 0;
    for (int i = 0; i < 98; ++i){ boff[i] = run; run += bsum[i]; }
  }
}
__global__ __launch_bounds__(256) void k_scan3(const int* __restrict__ part, const int* __restrict__ boff,
                                               int* rowptr, int* cursor){
  int i = blockIdx.x*256 + threadIdx.x;
  if (i < NN){ int v = part[i] + boff[i >> 10]; rowptr[i] = v; cursor[i] = v; }
  if (i == 0) rowptr[NN] = NN + NE;
}
__global__ __launch_bounds__(256) void k_fill(const int* __restrict__ ei, int* cursor, int* __restrict__ esrc){
  int i = blockIdx.x*256 + threadIdx.x;
  if (i < NE + NN){
    int s, d;
    if (i < NE){ s = ei[i]; d = ei[NE + i]; } else { s = d = i - NE; }
    int slot = atomicAdd(&cursor[d], 1);
    esrc[slot] = s;
  }
}

// ---------------- K3: layer-1 aggregation over fp8 xp1, edge-batched (8/batch). One wave per dst ----------------
__global__ __launch_bounds__(256) void k_agg1(const unsigned char* __restrict__ xp1,
    const float* __restrict__ asrc, const float* __restrict__ adst,
    const float* __restrict__ b1, const int* __restrict__ rowptr,
    const int* __restrict__ esrc, _Float16* __restrict__ h1)
{
  const int lane = threadIdx.x & 63;
  int n = __builtin_amdgcn_readfirstlane(blockIdx.x*4 + (threadIdx.x >> 6));
  const int h  = lane >> 3;     // channel-layout head
  const int le = lane >> 3;     // batch-layout edge slot
  const int lh = lane & 7;      // batch-layout head
  const float adl = adst[n*8 + lh];
  const int jb = rowptr[n], je = rowptr[n+1];
  const unsigned* xpw = (const unsigned*)xp1;   // row s = 64 dwords (256 fp8 ch)
  float4 acc = make_float4(0,0,0,0);
  float zacc = 0.f;

  for (int j0 = jb; j0 < je; j0 += 8) {
    const int cnt = je - j0;    // wave-uniform (SGPR)
    int sv = 0;
    if (lane < cnt && lane < 8) sv = esrc[j0 + lane];
    const int se = __shfl(sv, le, 64);
    float pv = 0.f;
    if (le < cnt) pv = __expf(leaky(asrc[se*8 + lh] + adl));
    zacc += pv;
    #pragma unroll
    for (int e = 0; e < 8; ++e) {
      if (e >= cnt) break;                        // uniform early-exit
      const float p = __shfl(pv, e*8 + h, 64);
      const int   s = __shfl(sv, e, 64);
      unsigned u = xpw[(size_t)s*64 + lane];      // 256B coalesced row (2 aligned lines)
      f2v lo = __builtin_amdgcn_cvt_pk_f32_fp8((int)u, false);  // bytes 0,1
      f2v hi = __builtin_amdgcn_cvt_pk_f32_fp8((int)u, true);   // bytes 2,3
      acc.x += p*lo.x; acc.y += p*lo.y;
      acc.z += p*hi.x; acc.w += p*hi.y;
    }
  }
  zacc += __shfl_xor(zacc, 8, 64);
  zacc += __shfl_xor(zacc, 16, 64);
  zacc += __shfl_xor(zacc, 32, 64);
  const float z = __shfl(zacc, h, 64);
  const float inv = 1.f / (z + 1e-16f);
  const float4 bb = ((const float4*)b1)[lane];
  h4 o = {(_Float16)fmaxf(acc.x*inv + bb.x, 0.f),
          (_Float16)fmaxf(acc.y*inv + bb.y, 0.f),
          (_Float16)fmaxf(acc.z*inv + bb.z, 0.f),
          (_Float16)fmaxf(acc.w*inv + bb.w, 0.f)};
  ((h4*)h1)[(size_t)n*64 + lane] = o;
}

// ---------------- K4: xp2 = h1 @ W2 via fp16 MFMA + layer-2 attention dots ----------------
// xp2 row stride = XPAD(64) fp16 = 128 B: each agg2 gather touches exactly one cacheline.
__global__ __launch_bounds__(256) void k_gemm2(const _Float16* __restrict__ h1,
    const _Float16* __restrict__ W2t, const float* __restrict__ attS,
    const float* __restrict__ attD, _Float16* __restrict__ xp2,
    float* __restrict__ asrc2, float* __restrict__ adst2)
{
  const int tid  = threadIdx.x;
  const int lane = tid & 63;
  const int w    = tid >> 6;
  const int n = lane & 15, quad = lane >> 4;
  const int r0 = blockIdx.x * 256 + w*64;

  float aSc[3], aDc[3];
  #pragma unroll
  for (int ct = 0; ct < 3; ++ct){
    int col = ct*16 + n;
    aSc[ct] = (col < OC) ? attS[col] : 0.f;
    aDc[ct] = (col < OC) ? attD[col] : 0.f;
  }

  f4v acc[4][3];
  #pragma unroll
  for (int rt = 0; rt < 4; ++rt)
    #pragma unroll
    for (int ct = 0; ct < 3; ++ct) acc[rt][ct] = (f4v){0.f,0.f,0.f,0.f};

  int rr[4];
  #pragma unroll
  for (int rt = 0; rt < 4; ++rt){
    int r = r0 + rt*16 + n;
    rr[rt] = (r < NN) ? r : NN-1;
  }

  #pragma unroll
  for (int ks = 0; ks < 8; ++ks){
    h8 b[3];
    #pragma unroll
    for (int ct = 0; ct < 3; ++ct)
      b[ct] = *(const h8*)(W2t + (size_t)(ct*16 + n)*256 + ks*32 + quad*8);
    #pragma unroll
    for (int rt = 0; rt < 4; ++rt){
      h8 a = *(const h8*)(h1 + (size_t)rr[rt]*256 + ks*32 + quad*8);
      #pragma unroll
      for (int ct = 0; ct < 3; ++ct)
        acc[rt][ct] = __builtin_amdgcn_mfma_f32_16x16x32_f16(a, b[ct], acc[rt][ct], 0, 0, 0);
    }
  }

  #pragma unroll
  for (int rt = 0; rt < 4; ++rt){
    #pragma unroll
    for (int reg = 0; reg < 4; ++reg){
      const int row = r0 + rt*16 + quad*4 + reg;
      const bool ok = row < NN;
      float v0 = acc[rt][0][reg], v1 = acc[rt][1][reg], v2 = acc[rt][2][reg];
      float s = v0*aSc[0] + v1*aSc[1] + v2*aSc[2];
      float d = v0*aDc[0] + v1*aDc[1] + v2*aDc[2];
      #pragma unroll
      for (int off = 1; off < 16; off <<= 1){
        s += __shfl_xor(s, off, 64);
        d += __shfl_xor(d, off, 64);
      }
      if (ok){
        _Float16* xr = xp2 + (size_t)row*XPAD + n;
        xr[0]  = (_Float16)v0;
        xr[16] = (_Float16)v1;
        if (n < 8) xr[32] = (_Float16)v2;
        if (n == 0){ asrc2[row] = s; adst2[row] = d; }
      }
    }
  }
}

// ---------------- K5: layer-2 aggregation, edge-batched (16/batch, uniform break). One wave per node ----------------
__global__ __launch_bounds__(256) void k_agg2(const _Float16* __restrict__ xp2,
    const float* __restrict__ asrc2, const float* __restrict__ adst2,
    const float* __restrict__ b2, const int* __restrict__ rowptr,
    const int* __restrict__ esrc, float* __restrict__ out)
{
  const int lane = threadIdx.x & 63;
  int n = __builtin_amdgcn_readfirstlane(blockIdx.x*4 + (threadIdx.x >> 6));
  const float ad = adst2[n];
  const int jb = rowptr[n], je = rowptr[n+1];
  const bool act = lane < OC;
  float acc = 0.f, zacc = 0.f;

  for (int j0 = jb; j0 < je; j0 += 16) {
    const int cnt = je - j0;    // wave-uniform
    int sv = 0;
    if (lane < cnt && lane < 16) sv = esrc[j0 + lane];
    float pv = 0.f;
    if (lane < cnt && lane < 16) pv = __expf(leaky(asrc2[sv] + ad));
    zacc += pv;
    #pragma unroll
    for (int e = 0; e < 16; ++e) {
      if (e >= cnt) break;                        // uniform early-exit
      const float p = __shfl(pv, e, 64);
      const int   s = __shfl(sv, e, 64);
      if (act) acc += p * (float)xp2[(size_t)s*XPAD + lane];  // one 128B line per row
    }
  }
  #pragma unroll
  for (int off = 1; off < 64; off <<= 1) zacc += __shfl_xor(zacc, off, 64);

  float val = act ? (acc/(zacc + 1e-16f) + b2[lane]) : -INFINITY;
  float m = val;
  #pragma unroll
  for (int off = 32; off > 0; off >>= 1) m = fmaxf(m, __shfl_xor(m, off, 64));
  float e = act ? __expf(val - m) : 0.f;
  float sum = e;
  #pragma unroll
  for (int off = 32; off > 0; off >>= 1) sum += __shfl_xor(sum, off, 64);
  if (act) out[(size_t)n*OC + lane] = val - m - __logf(sum);
}

extern "C" void kernel_launch(void* const* d_in, const int* in_sizes, int n_in,
                              void* d_out, int out_size, void* d_ws, size_t ws_size,
                              hipStream_t stream)
{
  const float* x   = (const float*)d_in[0];
  const int*   ei  = (const int*)  d_in[1];
  const float* W1  = (const float*)d_in[2];
  const float* aS1 = (const float*)d_in[3];
  const float* aD1 = (const float*)d_in[4];
  const float* b1  = (const float*)d_in[5];
  const float* W2  = (const float*)d_in[6];
  const float* aS2 = (const float*)d_in[7];
  const float* aD2 = (const float*)d_in[8];
  const float* b2  = (const float*)d_in[9];
  float* out = (float*)d_out;

  char* wsp = (char*)d_ws;
  size_t off = 0;
  auto alloc = [&](size_t bytes){ void* p = wsp + off; off += (bytes + 255) & ~(size_t)255; return p; };
  unsigned char* xp1 = (unsigned char*)alloc((size_t)NN*C1);   // fp8 e4m3; buffer reused as xp2 after agg1
  _Float16* h1  = (_Float16*)alloc((size_t)NN*C1*2);           // fp16
  float* as1  = (float*)alloc((size_t)NN*8*4);
  float* ad1  = (float*)alloc((size_t)NN*8*4);
  float* as2  = (float*)alloc((size_t)NN*4);
  float* ad2  = (float*)alloc((size_t)NN*4);
  int* deg    = (int*)alloc((size_t)NN*4);
  int* part   = (int*)alloc((size_t)NN*4);
  int* rowptr = (int*)alloc((size_t)(NN+1)*4);
  int* cursor = (int*)alloc((size_t)NN*4);
  int* bsum   = (int*)alloc(98*4);
  int* boff   = (int*)alloc(98*4);
  int* esrc   = (int*)alloc((size_t)(NN+NE)*4);
  _Float16* W1t = (_Float16*)alloc((size_t)256*128*2);
  _Float16* W2t = (_Float16*)alloc((size_t)48*256*2);
  _Float16* xp2 = (_Float16*)alloc((size_t)NN*XPAD*2);  // separate 12.8 MB region, 128B-aligned rows
  (void)ws_size; (void)in_sizes; (void)n_in; (void)out_size;

  k_w1t      <<<128,  256, 0, stream>>>(W1, W1t);
  k_w2t      <<<48,   256, 0, stream>>>(W2, W2t);
  k_gemm1    <<<1563, 256, 0, stream>>>(x, W1t, aS1, aD1, xp1, as1, ad1);
  k_deg_init <<<391,  256, 0, stream>>>(deg);
  k_deg_count<<<3125, 256, 0, stream>>>(ei, deg);
  k_scan1    <<<98,   256, 0, stream>>>(deg, part, bsum);
  k_scan2    <<<1,    64,  0, stream>>>(bsum, boff);
  k_scan3    <<<391,  256, 0, stream>>>(part, boff, rowptr, cursor);
  k_fill     <<<3516, 256, 0, stream>>>(ei, cursor, esrc);
  k_agg1     <<<25000,256, 0, stream>>>(xp1, as1, ad1, b1, rowptr, esrc, h1);
  k_gemm2    <<<391,  256, 0, stream>>>(h1, W2t, aS2, aD2, xp2, as2, ad2);
  k_agg2     <<<25000,256, 0, stream>>>(xp2, as2, ad2, b2, rowptr, esrc, out);
}

// Round 7
// 402.430 us; speedup vs baseline: 1.5743x; 1.0424x over previous
//
#include <hip/hip_runtime.h>
#include <math.h>

#define NN 100000
#define NE 800000
#define C1 256   // HEADS*HID
#define OC 40
#define XPAD 64  // padded xp2 row stride (fp16) = 128 B = 1 cacheline
#define NEG 0.2f

typedef _Float16 h4 __attribute__((ext_vector_type(4)));
typedef _Float16 h8 __attribute__((ext_vector_type(8)));
typedef float f4v __attribute__((ext_vector_type(4)));
typedef float f2v __attribute__((ext_vector_type(2)));

static __device__ __forceinline__ float leaky(float v){ return v > 0.f ? v : NEG*v; }

static __device__ __forceinline__ h8 cvt8(const float4* p){
  float4 a = p[0], b = p[1];
  h8 r = {(_Float16)a.x,(_Float16)a.y,(_Float16)a.z,(_Float16)a.w,
          (_Float16)b.x,(_Float16)b.y,(_Float16)b.z,(_Float16)b.w};
  return r;
}

// Permuted xp1/h1 row layout: storage element e = 4*l + j (l = dword/lane 0..63, j = byte 0..3)
// holds logical col pcol(l,j) = (l>>5)*128 + ((l>>4)&1)*64 + 16*j + (l&15).
// gemm1 packs 4 fp8 per dword (coalesced); agg1/h1/W2t all use the same permutation.

// ---------------- W1t (fp16 col-major) + W2t (fp16, k-permuted) in one launch ----------------
__global__ __launch_bounds__(256) void k_wt(const float* __restrict__ W1, const float* __restrict__ W2,
                                            _Float16* __restrict__ W1t, _Float16* __restrict__ W2t){
  int b = blockIdx.x;
  if (b < 128){
    int k = b, nb = threadIdx.x;
    W1t[(size_t)nb*128 + k] = (_Float16)W1[k*256 + nb];
  } else {
    int nb = b - 128;            // 0..47 (pad 40->48 with zeros)
    int e = threadIdx.x;         // storage index 0..255
    int l = e >> 2, j = e & 3;
    int k = (l>>5)*128 + ((l>>4)&1)*64 + j*16 + (l&15);   // logical k of storage slot e
    float v = (nb < OC) ? W2[(size_t)k*OC + nb] : 0.f;
    W2t[(size_t)nb*256 + e] = (_Float16)v;
  }
}

// ---------------- K1: xp1 = x @ W1 via fp16 MFMA -> packed fp8 dword stores + attention dots ----------------
__global__ __launch_bounds__(256) void k_gemm1(const float* __restrict__ x,
    const _Float16* __restrict__ W1t, const float* __restrict__ attS,
    const float* __restrict__ attD, unsigned* __restrict__ xp1w,
    float* __restrict__ asrc, float* __restrict__ adst)
{
  const int tid  = threadIdx.x;
  const int lane = tid & 63;
  const int w    = tid >> 6;
  const int wr = w >> 1, wc = w & 1;
  const int n = lane & 15, quad = lane >> 4;
  const int r0 = blockIdx.x * 64;

  float aSc[8], aDc[8];
  #pragma unroll
  for (int ct = 0; ct < 8; ++ct){
    int col = wc*128 + ct*16 + n;
    aSc[ct] = attS[col]; aDc[ct] = attD[col];
  }

  f4v acc[2][8];
  #pragma unroll
  for (int rt = 0; rt < 2; ++rt)
    #pragma unroll
    for (int ct = 0; ct < 8; ++ct) acc[rt][ct] = (f4v){0.f,0.f,0.f,0.f};

  const int row0 = r0 + wr*32 + n;
  const int ra = (row0      < NN) ? row0      : NN-1;
  const int rb = (row0 + 16 < NN) ? row0 + 16 : NN-1;

  #pragma unroll
  for (int ks = 0; ks < 4; ++ks){
    h8 a0 = cvt8((const float4*)(x + (size_t)ra*128 + ks*32 + quad*8));
    h8 a1 = cvt8((const float4*)(x + (size_t)rb*128 + ks*32 + quad*8));
    #pragma unroll
    for (int ct = 0; ct < 8; ++ct){
      h8 b = *(const h8*)(W1t + (size_t)(wc*128 + ct*16 + n)*128 + ks*32 + quad*8);
      acc[0][ct] = __builtin_amdgcn_mfma_f32_16x16x32_f16(a0, b, acc[0][ct], 0, 0, 0);
      acc[1][ct] = __builtin_amdgcn_mfma_f32_16x16x32_f16(a1, b, acc[1][ct], 0, 0, 0);
    }
  }

  #pragma unroll
  for (int rt = 0; rt < 2; ++rt){
    #pragma unroll
    for (int reg = 0; reg < 4; ++reg){
      const int row = r0 + wr*32 + rt*16 + quad*4 + reg;
      const bool ok = row < NN;
      float v[8];
      #pragma unroll
      for (int ct = 0; ct < 8; ++ct) v[ct] = acc[rt][ct][reg];
      if (ok){
        // pack v[0..3] -> dword at storage l = wc*32+n; v[4..7] -> l = wc*32+16+n
        unsigned dwA = (unsigned)__builtin_amdgcn_cvt_pk_fp8_f32(v[0], v[1], 0, false);
        dwA = (unsigned)__builtin_amdgcn_cvt_pk_fp8_f32(v[2], v[3], (int)dwA, true);
        unsigned dwB = (unsigned)__builtin_amdgcn_cvt_pk_fp8_f32(v[4], v[5], 0, false);
        dwB = (unsigned)__builtin_amdgcn_cvt_pk_fp8_f32(v[6], v[7], (int)dwB, true);
        unsigned* xr = xp1w + (size_t)row*64 + wc*32 + n;
        xr[0]  = dwA;
        xr[16] = dwB;
      }
      float s[4], d[4];
      #pragma unroll
      for (int h = 0; h < 4; ++h){
        s[h] = v[2*h]*aSc[2*h] + v[2*h+1]*aSc[2*h+1];
        d[h] = v[2*h]*aDc[2*h] + v[2*h+1]*aDc[2*h+1];
      }
      #pragma unroll
      for (int off = 1; off < 16; off <<= 1){
        #pragma unroll
        for (int h = 0; h < 4; ++h){
          s[h] += __shfl_xor(s[h], off, 64);
          d[h] += __shfl_xor(d[h], off, 64);
        }
      }
      if (ok && n == 0){
        #pragma unroll
        for (int h = 0; h < 4; ++h){
          asrc[row*8 + wc*4 + h] = s[h];
          adst[row*8 + wc*4 + h] = d[h];
        }
      }
    }
  }
}

// ---------------- CSR build (dst-sorted), self-loop slot reserved via deg init = 1 ----------------
__global__ __launch_bounds__(256) void k_deg_init(int* deg){
  int i = blockIdx.x*256 + threadIdx.x;
  if (i < NN) deg[i] = 1;
}
__global__ __launch_bounds__(256) void k_deg_count(const int* __restrict__ ei, int* deg){
  int i = blockIdx.x*256 + threadIdx.x;
  if (i < NE) atomicAdd(&deg[ei[NE + i]], 1);
}
__global__ __launch_bounds__(256) void k_scan1(const int* __restrict__ deg, int* part, int* bsum){
  __shared__ int lds[256];
  const int t = threadIdx.x;
  const int base = blockIdx.x*1024;
  int v[4]; int s = 0;
  #pragma unroll
  for (int i = 0; i < 4; ++i){ int idx = base + t*4 + i; v[i] = (idx < NN) ? deg[idx] : 0; s += v[i]; }
  lds[t] = s; __syncthreads();
  for (int off = 1; off < 256; off <<= 1){
    int xx = (t >= off) ? lds[t-off] : 0;
    __syncthreads();
    lds[t] += xx;
    __syncthreads();
  }
  int excl = lds[t] - s;
  #pragma unroll
  for (int i = 0; i < 4; ++i){ int idx = base + t*4 + i; if (idx < NN) part[idx] = excl; excl += v[i]; }
  if (t == 255) bsum[blockIdx.x] = lds[255];
}
// wave-parallel scan over the 98 block sums (was: 98 serial global round-trips)
__global__ void k_scan2(const int* __restrict__ bsum, int* boff){
  const int l = threadIdx.x;   // 64 threads, lane i handles elements i and 64+i
  int a = (l      < 98) ? bsum[l]      : 0;
  int b = (64 + l < 98) ? bsum[64 + l] : 0;
  int sa = a, sb = b;
  #pragma unroll
  for (int off = 1; off < 64; off <<= 1){
    int ta = __shfl_up(sa, off, 64);
    int tb = __shfl_up(sb, off, 64);
    if (l >= off){ sa += ta; sb += tb; }
  }
  const int totalA = __shfl(sa, 63, 64);
  if (l      < 98) boff[l]      = sa - a;
  if (64 + l < 98) boff[64 + l] = totalA + sb - b;
}
__global__ __launch_bounds__(256) void k_scan3(const int* __restrict__ part, const int* __restrict__ boff,
                                               int* rowptr, int* cursor){
  int i = blockIdx.x*256 + threadIdx.x;
  if (i < NN){ int v = part[i] + boff[i >> 10]; rowptr[i] = v; cursor[i] = v; }
  if (i == 0) rowptr[NN] = NN + NE;
}
__global__ __launch_bounds__(256) void k_fill(const int* __restrict__ ei, int* cursor, int* __restrict__ esrc){
  int i = blockIdx.x*256 + threadIdx.x;
  if (i < NE + NN){
    int s, d;
    if (i < NE){ s = ei[i]; d = ei[NE + i]; } else { s = d = i - NE; }
    int slot = atomicAdd(&cursor[d], 1);
    esrc[slot] = s;
  }
}

// ---------------- K3: layer-1 aggregation over permuted fp8 xp1, two-phase 8-batch ----------------
__global__ __launch_bounds__(256) void k_agg1(const unsigned* __restrict__ xp1w,
    const float* __restrict__ asrc, const float* __restrict__ adst,
    const float* __restrict__ b1, const int* __restrict__ rowptr,
    const int* __restrict__ esrc, _Float16* __restrict__ h1)
{
  const int lane = threadIdx.x & 63;
  int n = __builtin_amdgcn_readfirstlane(blockIdx.x*4 + (threadIdx.x >> 6));
  const int hA = (lane >> 4) * 2;     // my 4 channels belong to heads hA (j=0,1) and hA+1 (j=2,3)
  const int le = lane >> 3;           // batch layout: edge slot
  const int lh = lane & 7;            // batch layout: head
  const float adl = adst[n*8 + lh];
  const int jb = rowptr[n], je = rowptr[n+1];
  // permuted bias: my cols are cbase + 16j
  const int cbase = (lane>>5)*128 + ((lane>>4)&1)*64 + (lane&15);
  const float bp0 = b1[cbase], bp1 = b1[cbase+16], bp2 = b1[cbase+32], bp3 = b1[cbase+48];
  float4 acc = make_float4(0,0,0,0);
  float zacc = 0.f;

  for (int j0 = jb; j0 < je; j0 += 8) {
    const int cnt = je - j0;          // wave-uniform
    int sv = 0;
    if (lane < 8 && lane < cnt) sv = esrc[j0 + lane];
    const int se = __shfl(sv, le, 64);
    float pv = 0.f;
    if (le < cnt) pv = __expf(leaky(asrc[se*8 + lh] + adl));
    zacc += pv;
    // phase 1: issue all row loads (SGPR base + shared lane offset -> all in flight)
    unsigned u[8];
    #pragma unroll
    for (int e = 0; e < 8; ++e){
      if (e < cnt){
        int s = __builtin_amdgcn_readfirstlane(__shfl(sv, e, 64));
        u[e] = xp1w[(size_t)s*64 + lane];
      }
    }
    // phase 2: decode + fma
    #pragma unroll
    for (int e = 0; e < 8; ++e){
      if (e < cnt){
        const float pA = __shfl(pv, e*8 + hA,     64);
        const float pB = __shfl(pv, e*8 + hA + 1, 64);
        f2v lo = __builtin_amdgcn_cvt_pk_f32_fp8((int)u[e], false);
        f2v hi = __builtin_amdgcn_cvt_pk_f32_fp8((int)u[e], true);
        acc.x += pA*lo.x; acc.y += pA*lo.y;
        acc.z += pB*hi.x; acc.w += pB*hi.y;
      }
    }
  }
  zacc += __shfl_xor(zacc, 8, 64);
  zacc += __shfl_xor(zacc, 16, 64);
  zacc += __shfl_xor(zacc, 32, 64);
  const float zA = __shfl(zacc, hA, 64), zB = __shfl(zacc, hA+1, 64);
  const float invA = 1.f/(zA + 1e-16f), invB = 1.f/(zB + 1e-16f);
  h4 o = {(_Float16)fmaxf(acc.x*invA + bp0, 0.f),
          (_Float16)fmaxf(acc.y*invA + bp1, 0.f),
          (_Float16)fmaxf(acc.z*invB + bp2, 0.f),
          (_Float16)fmaxf(acc.w*invB + bp3, 0.f)};
  ((h4*)h1)[(size_t)n*64 + lane] = o;   // h1 inherits the permuted col order
}

// ---------------- K4: xp2 = h1 @ W2 via fp16 MFMA (k in permuted order on both A and B) ----------------
__global__ __launch_bounds__(256) void k_gemm2(const _Float16* __restrict__ h1,
    const _Float16* __restrict__ W2t, const float* __restrict__ attS,
    const float* __restrict__ attD, _Float16* __restrict__ xp2,
    float* __restrict__ asrc2, float* __restrict__ adst2)
{
  const int tid  = threadIdx.x;
  const int lane = tid & 63;
  const int w    = tid >> 6;
  const int n = lane & 15, quad = lane >> 4;
  const int r0 = blockIdx.x * 256 + w*64;

  float aSc[3], aDc[3];
  #pragma unroll
  for (int ct = 0; ct < 3; ++ct){
    int col = ct*16 + n;
    aSc[ct] = (col < OC) ? attS[col] : 0.f;
    aDc[ct] = (col < OC) ? attD[col] : 0.f;
  }

  f4v acc[4][3];
  #pragma unroll
  for (int rt = 0; rt < 4; ++rt)
    #pragma unroll
    for (int ct = 0; ct < 3; ++ct) acc[rt][ct] = (f4v){0.f,0.f,0.f,0.f};

  int rr[4];
  #pragma unroll
  for (int rt = 0; rt < 4; ++rt){
    int r = r0 + rt*16 + n;
    rr[rt] = (r < NN) ? r : NN-1;
  }

  #pragma unroll
  for (int ks = 0; ks < 8; ++ks){
    h8 b[3];
    #pragma unroll
    for (int ct = 0; ct < 3; ++ct)
      b[ct] = *(const h8*)(W2t + (size_t)(ct*16 + n)*256 + ks*32 + quad*8);
    #pragma unroll
    for (int rt = 0; rt < 4; ++rt){
      h8 a = *(const h8*)(h1 + (size_t)rr[rt]*256 + ks*32 + quad*8);
      #pragma unroll
      for (int ct = 0; ct < 3; ++ct)
        acc[rt][ct] = __builtin_amdgcn_mfma_f32_16x16x32_f16(a, b[ct], acc[rt][ct], 0, 0, 0);
    }
  }

  #pragma unroll
  for (int rt = 0; rt < 4; ++rt){
    #pragma unroll
    for (int reg = 0; reg < 4; ++reg){
      const int row = r0 + rt*16 + quad*4 + reg;
      const bool ok = row < NN;
      float v0 = acc[rt][0][reg], v1 = acc[rt][1][reg], v2 = acc[rt][2][reg];
      float s = v0*aSc[0] + v1*aSc[1] + v2*aSc[2];
      float d = v0*aDc[0] + v1*aDc[1] + v2*aDc[2];
      #pragma unroll
      for (int off = 1; off < 16; off <<= 1){
        s += __shfl_xor(s, off, 64);
        d += __shfl_xor(d, off, 64);
      }
      if (ok){
        _Float16* xr = xp2 + (size_t)row*XPAD + n;
        xr[0]  = (_Float16)v0;
        xr[16] = (_Float16)v1;
        if (n < 8) xr[32] = (_Float16)v2;
        if (n == 0){ asrc2[row] = s; adst2[row] = d; }
      }
    }
  }
}

// ---------------- K5: layer-2 aggregation, two-phase 16-batch. One wave per node ----------------
__global__ __launch_bounds__(256) void k_agg2(const _Float16* __restrict__ xp2,
    const float* __restrict__ asrc2, const float* __restrict__ adst2,
    const float* __restrict__ b2, const int* __restrict__ rowptr,
    const int* __restrict__ esrc, float* __restrict__ out)
{
  const int lane = threadIdx.x & 63;
  int n = __builtin_amdgcn_readfirstlane(blockIdx.x*4 + (threadIdx.x >> 6));
  const float ad = adst2[n];
  const int jb = rowptr[n], je = rowptr[n+1];
  const bool act = lane < OC;
  float acc = 0.f, zacc = 0.f;

  for (int j0 = jb; j0 < je; j0 += 16) {
    const int cnt = je - j0;          // wave-uniform
    int sv = 0;
    if (lane < 16 && lane < cnt) sv = esrc[j0 + lane];
    float pv = 0.f;
    if (lane < 16 && lane < cnt) pv = __expf(leaky(asrc2[sv] + ad));
    zacc += pv;
    // phase 1: all row loads in flight (padded row covers all 64 lanes)
    _Float16 u[16];
    #pragma unroll
    for (int e = 0; e < 16; ++e){
      if (e < cnt){
        int s = __builtin_amdgcn_readfirstlane(__shfl(sv, e, 64));
        u[e] = xp2[(size_t)s*XPAD + lane];
      }
    }
    // phase 2: fma
    #pragma unroll
    for (int e = 0; e < 16; ++e){
      if (e < cnt){
        const float p = __shfl(pv, e, 64);
        acc += p * (float)u[e];
      }
    }
  }
  #pragma unroll
  for (int off = 1; off < 64; off <<= 1) zacc += __shfl_xor(zacc, off, 64);

  float val = act ? (acc/(zacc + 1e-16f) + b2[lane]) : -INFINITY;
  float m = val;
  #pragma unroll
  for (int off = 32; off > 0; off >>= 1) m = fmaxf(m, __shfl_xor(m, off, 64));
  float e = act ? __expf(val - m) : 0.f;
  float sum = e;
  #pragma unroll
  for (int off = 32; off > 0; off >>= 1) sum += __shfl_xor(sum, off, 64);
  if (act) out[(size_t)n*OC + lane] = val - m - __logf(sum);
}

extern "C" void kernel_launch(void* const* d_in, const int* in_sizes, int n_in,
                              void* d_out, int out_size, void* d_ws, size_t ws_size,
                              hipStream_t stream)
{
  const float* x   = (const float*)d_in[0];
  const int*   ei  = (const int*)  d_in[1];
  const float* W1  = (const float*)d_in[2];
  const float* aS1 = (const float*)d_in[3];
  const float* aD1 = (const float*)d_in[4];
  const float* b1  = (const float*)d_in[5];
  const float* W2  = (const float*)d_in[6];
  const float* aS2 = (const float*)d_in[7];
  const float* aD2 = (const float*)d_in[8];
  const float* b2  = (const float*)d_in[9];
  float* out = (float*)d_out;

  char* wsp = (char*)d_ws;
  size_t off = 0;
  auto alloc = [&](size_t bytes){ void* p = wsp + off; off += (bytes + 255) & ~(size_t)255; return p; };
  unsigned* xp1w = (unsigned*)alloc((size_t)NN*C1);            // fp8, permuted, 64 dwords/row
  _Float16* h1  = (_Float16*)alloc((size_t)NN*C1*2);           // fp16, permuted cols
  float* as1  = (float*)alloc((size_t)NN*8*4);
  float* ad1  = (float*)alloc((size_t)NN*8*4);
  float* as2  = (float*)alloc((size_t)NN*4);
  float* ad2  = (float*)alloc((size_t)NN*4);
  int* deg    = (int*)alloc((size_t)NN*4);
  int* part   = (int*)alloc((size_t)NN*4);
  int* rowptr = (int*)alloc((size_t)(NN+1)*4);
  int* cursor = (int*)alloc((size_t)NN*4);
  int* bsum   = (int*)alloc(98*4);
  int* boff   = (int*)alloc(98*4);
  int* esrc   = (int*)alloc((size_t)(NN+NE)*4);
  _Float16* W1t = (_Float16*)alloc((size_t)256*128*2);
  _Float16* W2t = (_Float16*)alloc((size_t)48*256*2);
  _Float16* xp2 = (_Float16*)alloc((size_t)NN*XPAD*2);  // 12.8 MB, 128B-aligned rows
  (void)ws_size; (void)in_sizes; (void)n_in; (void)out_size;

  k_wt       <<<176,  256, 0, stream>>>(W1, W2, W1t, W2t);
  k_gemm1    <<<1563, 256, 0, stream>>>(x, W1t, aS1, aD1, xp1w, as1, ad1);
  k_deg_init <<<391,  256, 0, stream>>>(deg);
  k_deg_count<<<3125, 256, 0, stream>>>(ei, deg);
  k_scan1    <<<98,   256, 0, stream>>>(deg, part, bsum);
  k_scan2    <<<1,    64,  0, stream>>>(bsum, boff);
  k_scan3    <<<391,  256, 0, stream>>>(part, boff, rowptr, cursor);
  k_fill     <<<3516, 256, 0, stream>>>(ei, cursor, esrc);
  k_agg1     <<<25000,256, 0, stream>>>(xp1w, as1, ad1, b1, rowptr, esrc, h1);
  k_gemm2    <<<391,  256, 0, stream>>>(h1, W2t, aS2, aD2, xp2, as2, ad2);
  k_agg2     <<<25000,256, 0, stream>>>(xp2, as2, ad2, b2, rowptr, esrc, out);
}

// Round 8
// 387.104 us; speedup vs baseline: 1.6367x; 1.0396x over previous
//
#include <hip/hip_runtime.h>
#include <math.h>

#define NN 100000
#define NE 800000
#define C1 256   // HEADS*HID
#define OC 40
#define XPAD 64  // padded xp2 row stride (fp16) = 128 B = 1 cacheline
#define NEG 0.2f

typedef _Float16 h4 __attribute__((ext_vector_type(4)));
typedef _Float16 h8 __attribute__((ext_vector_type(8)));
typedef float f4v __attribute__((ext_vector_type(4)));
typedef float f2v __attribute__((ext_vector_type(2)));

static __device__ __forceinline__ float leaky(float v){ return v > 0.f ? v : NEG*v; }

static __device__ __forceinline__ h8 cvt8(const float4* p){
  float4 a = p[0], b = p[1];
  h8 r = {(_Float16)a.x,(_Float16)a.y,(_Float16)a.z,(_Float16)a.w,
          (_Float16)b.x,(_Float16)b.y,(_Float16)b.z,(_Float16)b.w};
  return r;
}

// Permuted xp1/h1 row layout: storage element e = 4*l + j (l = dword/lane 0..63, j = byte 0..3)
// holds logical col pcol(l,j) = (l>>5)*128 + ((l>>4)&1)*64 + 16*j + (l&15).

// ---------------- W1t (fp16 col-major) + W2t (fp16, k-permuted) in one launch ----------------
__global__ __launch_bounds__(256) void k_wt(const float* __restrict__ W1, const float* __restrict__ W2,
                                            _Float16* __restrict__ W1t, _Float16* __restrict__ W2t){
  int b = blockIdx.x;
  if (b < 128){
    int k = b, nb = threadIdx.x;
    W1t[(size_t)nb*128 + k] = (_Float16)W1[k*256 + nb];
  } else {
    int nb = b - 128;            // 0..47 (pad 40->48 with zeros)
    int e = threadIdx.x;         // storage index 0..255
    int l = e >> 2, j = e & 3;
    int k = (l>>5)*128 + ((l>>4)&1)*64 + j*16 + (l&15);   // logical k of storage slot e
    float v = (nb < OC) ? W2[(size_t)k*OC + nb] : 0.f;
    W2t[(size_t)nb*256 + e] = (_Float16)v;
  }
}

// ---------------- K1: xp1 = x @ W1 via fp16 MFMA -> packed fp8 dword stores + attention dots ----------------
__global__ __launch_bounds__(256) void k_gemm1(const float* __restrict__ x,
    const _Float16* __restrict__ W1t, const float* __restrict__ attS,
    const float* __restrict__ attD, unsigned* __restrict__ xp1w,
    float* __restrict__ asrc, float* __restrict__ adst)
{
  const int tid  = threadIdx.x;
  const int lane = tid & 63;
  const int w    = tid >> 6;
  const int wr = w >> 1, wc = w & 1;
  const int n = lane & 15, quad = lane >> 4;
  const int r0 = blockIdx.x * 64;

  float aSc[8], aDc[8];
  #pragma unroll
  for (int ct = 0; ct < 8; ++ct){
    int col = wc*128 + ct*16 + n;
    aSc[ct] = attS[col]; aDc[ct] = attD[col];
  }

  f4v acc[2][8];
  #pragma unroll
  for (int rt = 0; rt < 2; ++rt)
    #pragma unroll
    for (int ct = 0; ct < 8; ++ct) acc[rt][ct] = (f4v){0.f,0.f,0.f,0.f};

  const int row0 = r0 + wr*32 + n;
  const int ra = (row0      < NN) ? row0      : NN-1;
  const int rb = (row0 + 16 < NN) ? row0 + 16 : NN-1;

  #pragma unroll
  for (int ks = 0; ks < 4; ++ks){
    h8 a0 = cvt8((const float4*)(x + (size_t)ra*128 + ks*32 + quad*8));
    h8 a1 = cvt8((const float4*)(x + (size_t)rb*128 + ks*32 + quad*8));
    #pragma unroll
    for (int ct = 0; ct < 8; ++ct){
      h8 b = *(const h8*)(W1t + (size_t)(wc*128 + ct*16 + n)*128 + ks*32 + quad*8);
      acc[0][ct] = __builtin_amdgcn_mfma_f32_16x16x32_f16(a0, b, acc[0][ct], 0, 0, 0);
      acc[1][ct] = __builtin_amdgcn_mfma_f32_16x16x32_f16(a1, b, acc[1][ct], 0, 0, 0);
    }
  }

  #pragma unroll
  for (int rt = 0; rt < 2; ++rt){
    #pragma unroll
    for (int reg = 0; reg < 4; ++reg){
      const int row = r0 + wr*32 + rt*16 + quad*4 + reg;
      const bool ok = row < NN;
      float v[8];
      #pragma unroll
      for (int ct = 0; ct < 8; ++ct) v[ct] = acc[rt][ct][reg];
      if (ok){
        unsigned dwA = (unsigned)__builtin_amdgcn_cvt_pk_fp8_f32(v[0], v[1], 0, false);
        dwA = (unsigned)__builtin_amdgcn_cvt_pk_fp8_f32(v[2], v[3], (int)dwA, true);
        unsigned dwB = (unsigned)__builtin_amdgcn_cvt_pk_fp8_f32(v[4], v[5], 0, false);
        dwB = (unsigned)__builtin_amdgcn_cvt_pk_fp8_f32(v[6], v[7], (int)dwB, true);
        unsigned* xr = xp1w + (size_t)row*64 + wc*32 + n;
        xr[0]  = dwA;
        xr[16] = dwB;
      }
      float s[4], d[4];
      #pragma unroll
      for (int h = 0; h < 4; ++h){
        s[h] = v[2*h]*aSc[2*h] + v[2*h+1]*aSc[2*h+1];
        d[h] = v[2*h]*aDc[2*h] + v[2*h+1]*aDc[2*h+1];
      }
      #pragma unroll
      for (int off = 1; off < 16; off <<= 1){
        #pragma unroll
        for (int h = 0; h < 4; ++h){
          s[h] += __shfl_xor(s[h], off, 64);
          d[h] += __shfl_xor(d[h], off, 64);
        }
      }
      if (ok && n == 0){
        #pragma unroll
        for (int h = 0; h < 4; ++h){
          asrc[row*8 + wc*4 + h] = s[h];
          adst[row*8 + wc*4 + h] = d[h];
        }
      }
    }
  }
}

// ---------------- CSR build (dst-sorted), self-loop slot reserved via deg init = 1 ----------------
__global__ __launch_bounds__(256) void k_deg_init(int* deg){
  int i = blockIdx.x*256 + threadIdx.x;
  if (i < NN) deg[i] = 1;
}
__global__ __launch_bounds__(256) void k_deg_count(const int* __restrict__ ei, int* deg){
  int i = blockIdx.x*256 + threadIdx.x;
  if (i < NE) atomicAdd(&deg[ei[NE + i]], 1);
}
__global__ __launch_bounds__(256) void k_scan1(const int* __restrict__ deg, int* part, int* bsum){
  __shared__ int lds[256];
  const int t = threadIdx.x;
  const int base = blockIdx.x*1024;
  int v[4]; int s = 0;
  #pragma unroll
  for (int i = 0; i < 4; ++i){ int idx = base + t*4 + i; v[i] = (idx < NN) ? deg[idx] : 0; s += v[i]; }
  lds[t] = s; __syncthreads();
  for (int off = 1; off < 256; off <<= 1){
    int xx = (t >= off) ? lds[t-off] : 0;
    __syncthreads();
    lds[t] += xx;
    __syncthreads();
  }
  int excl = lds[t] - s;
  #pragma unroll
  for (int i = 0; i < 4; ++i){ int idx = base + t*4 + i; if (idx < NN) part[idx] = excl; excl += v[i]; }
  if (t == 255) bsum[blockIdx.x] = lds[255];
}
__global__ void k_scan2(const int* __restrict__ bsum, int* boff){
  const int l = threadIdx.x;   // 64 threads, lane i handles elements i and 64+i
  int a = (l      < 98) ? bsum[l]      : 0;
  int b = (64 + l < 98) ? bsum[64 + l] : 0;
  int sa = a, sb = b;
  #pragma unroll
  for (int off = 1; off < 64; off <<= 1){
    int ta = __shfl_up(sa, off, 64);
    int tb = __shfl_up(sb, off, 64);
    if (l >= off){ sa += ta; sb += tb; }
  }
  const int totalA = __shfl(sa, 63, 64);
  if (l      < 98) boff[l]      = sa - a;
  if (64 + l < 98) boff[64 + l] = totalA + sb - b;
}
__global__ __launch_bounds__(256) void k_scan3(const int* __restrict__ part, const int* __restrict__ boff,
                                               int* rowptr, int* cursor){
  int i = blockIdx.x*256 + threadIdx.x;
  if (i < NN){ int v = part[i] + boff[i >> 10]; rowptr[i] = v; cursor[i] = v; }
  if (i == 0) rowptr[NN] = NN + NE;
}
__global__ __launch_bounds__(256) void k_fill(const int* __restrict__ ei, int* cursor, int* __restrict__ esrc){
  int i = blockIdx.x*256 + threadIdx.x;
  if (i < NE + NN){
    int s, d;
    if (i < NE){ s = ei[i]; d = ei[NE + i]; } else { s = d = i - NE; }
    int slot = atomicAdd(&cursor[d], 1);
    esrc[slot] = s;
  }
}

// ---------------- K3: layer-1 aggregation, branchless 8-batch, loads pinned before FMAs ----------------
__global__ __launch_bounds__(256) void k_agg1(const unsigned* __restrict__ xp1w,
    const float* __restrict__ asrc, const float* __restrict__ adst,
    const float* __restrict__ b1, const int* __restrict__ rowptr,
    const int* __restrict__ esrc, _Float16* __restrict__ h1)
{
  const int lane = threadIdx.x & 63;
  int n = __builtin_amdgcn_readfirstlane(blockIdx.x*4 + (threadIdx.x >> 6));
  const int hA = (lane >> 4) * 2;     // my 4 channels: heads hA (bytes 0,1), hA+1 (bytes 2,3)
  const int le = lane >> 3;           // batch layout: edge slot
  const int lh = lane & 7;            // batch layout: head
  const float adl = adst[n*8 + lh];
  const int jb = rowptr[n], je = rowptr[n+1];
  const int cbase = (lane>>5)*128 + ((lane>>4)&1)*64 + (lane&15);
  const float bp0 = b1[cbase], bp1 = b1[cbase+16], bp2 = b1[cbase+32], bp3 = b1[cbase+48];
  float4 acc = make_float4(0,0,0,0);
  float zacc = 0.f;

  for (int j0 = jb; j0 < je; j0 += 8) {
    const int cnt = je - j0;          // wave-uniform
    // clamped batch index: always valid, padded slots repeat last edge
    int idx = j0 + (lane & 7); idx = idx < je ? idx : je - 1;
    const int sv = esrc[idx];
    const int se = __shfl(sv, le*8, 64);   // any lane of slot le (all 8 hold same sv per slot? no:)
    // NB: lanes 0..7 hold slots 0..7; lanes 8..63 hold repeats via (lane&7). se from lane le works:
    const float pv = (le < cnt) ? __expf(leaky(asrc[__shfl(sv, le, 64)*8 + lh] + adl)) : 0.f;
    zacc += pv;
    // phase 1: 8 unconditional row loads from clamped SGPR bases
    unsigned u[8];
    #pragma unroll
    for (int e = 0; e < 8; ++e){
      int s = __builtin_amdgcn_readfirstlane(__shfl(sv, e, 64));
      u[e] = xp1w[(size_t)s*64 + lane];
    }
    __builtin_amdgcn_sched_barrier(0);   // pin: all loads issued before any FMA below
    // phase 2: decode + fma (p = 0 for padded slots -> garbage-free)
    #pragma unroll
    for (int e = 0; e < 8; ++e){
      const float pA = __shfl(pv, e*8 + hA,     64);
      const float pB = __shfl(pv, e*8 + hA + 1, 64);
      f2v lo = __builtin_amdgcn_cvt_pk_f32_fp8((int)u[e], false);
      f2v hi = __builtin_amdgcn_cvt_pk_f32_fp8((int)u[e], true);
      acc.x += pA*lo.x; acc.y += pA*lo.y;
      acc.z += pB*hi.x; acc.w += pB*hi.y;
    }
  }
  zacc += __shfl_xor(zacc, 8, 64);
  zacc += __shfl_xor(zacc, 16, 64);
  zacc += __shfl_xor(zacc, 32, 64);
  const float zA = __shfl(zacc, hA, 64), zB = __shfl(zacc, hA+1, 64);
  const float invA = 1.f/(zA + 1e-16f), invB = 1.f/(zB + 1e-16f);
  h4 o = {(_Float16)fmaxf(acc.x*invA + bp0, 0.f),
          (_Float16)fmaxf(acc.y*invA + bp1, 0.f),
          (_Float16)fmaxf(acc.z*invB + bp2, 0.f),
          (_Float16)fmaxf(acc.w*invB + bp3, 0.f)};
  ((h4*)h1)[(size_t)n*64 + lane] = o;   // h1 inherits the permuted col order
}

// ---------------- K4: xp2 = h1 @ W2 via fp16 MFMA (k in permuted order on both A and B) ----------------
__global__ __launch_bounds__(256) void k_gemm2(const _Float16* __restrict__ h1,
    const _Float16* __restrict__ W2t, const float* __restrict__ attS,
    const float* __restrict__ attD, _Float16* __restrict__ xp2,
    float* __restrict__ asrc2, float* __restrict__ adst2)
{
  const int tid  = threadIdx.x;
  const int lane = tid & 63;
  const int w    = tid >> 6;
  const int n = lane & 15, quad = lane >> 4;
  const int r0 = blockIdx.x * 256 + w*64;

  float aSc[3], aDc[3];
  #pragma unroll
  for (int ct = 0; ct < 3; ++ct){
    int col = ct*16 + n;
    aSc[ct] = (col < OC) ? attS[col] : 0.f;
    aDc[ct] = (col < OC) ? attD[col] : 0.f;
  }

  f4v acc[4][3];
  #pragma unroll
  for (int rt = 0; rt < 4; ++rt)
    #pragma unroll
    for (int ct = 0; ct < 3; ++ct) acc[rt][ct] = (f4v){0.f,0.f,0.f,0.f};

  int rr[4];
  #pragma unroll
  for (int rt = 0; rt < 4; ++rt){
    int r = r0 + rt*16 + n;
    rr[rt] = (r < NN) ? r : NN-1;
  }

  #pragma unroll
  for (int ks = 0; ks < 8; ++ks){
    h8 b[3];
    #pragma unroll
    for (int ct = 0; ct < 3; ++ct)
      b[ct] = *(const h8*)(W2t + (size_t)(ct*16 + n)*256 + ks*32 + quad*8);
    #pragma unroll
    for (int rt = 0; rt < 4; ++rt){
      h8 a = *(const h8*)(h1 + (size_t)rr[rt]*256 + ks*32 + quad*8);
      #pragma unroll
      for (int ct = 0; ct < 3; ++ct)
        acc[rt][ct] = __builtin_amdgcn_mfma_f32_16x16x32_f16(a, b[ct], acc[rt][ct], 0, 0, 0);
    }
  }

  #pragma unroll
  for (int rt = 0; rt < 4; ++rt){
    #pragma unroll
    for (int reg = 0; reg < 4; ++reg){
      const int row = r0 + rt*16 + quad*4 + reg;
      const bool ok = row < NN;
      float v0 = acc[rt][0][reg], v1 = acc[rt][1][reg], v2 = acc[rt][2][reg];
      float s = v0*aSc[0] + v1*aSc[1] + v2*aSc[2];
      float d = v0*aDc[0] + v1*aDc[1] + v2*aDc[2];
      #pragma unroll
      for (int off = 1; off < 16; off <<= 1){
        s += __shfl_xor(s, off, 64);
        d += __shfl_xor(d, off, 64);
      }
      if (ok){
        _Float16* xr = xp2 + (size_t)row*XPAD + n;
        xr[0]  = (_Float16)v0;
        xr[16] = (_Float16)v1;
        if (n < 8) xr[32] = (_Float16)v2;
        if (n == 0){ asrc2[row] = s; adst2[row] = d; }
      }
    }
  }
}

// ---------------- K5: layer-2 aggregation, branchless 16-batch, loads pinned before FMAs ----------------
__global__ __launch_bounds__(256) void k_agg2(const _Float16* __restrict__ xp2,
    const float* __restrict__ asrc2, const float* __restrict__ adst2,
    const float* __restrict__ b2, const int* __restrict__ rowptr,
    const int* __restrict__ esrc, float* __restrict__ out)
{
  const int lane = threadIdx.x & 63;
  int n = __builtin_amdgcn_readfirstlane(blockIdx.x*4 + (threadIdx.x >> 6));
  const float ad = adst2[n];
  const int jb = rowptr[n], je = rowptr[n+1];
  const bool act = lane < OC;
  float acc = 0.f, zacc = 0.f;

  for (int j0 = jb; j0 < je; j0 += 16) {
    const int cnt = je - j0;          // wave-uniform
    int idx = j0 + (lane & 15); idx = idx < je ? idx : je - 1;   // clamped, always valid
    const int sv = esrc[idx];
    const float pv = (lane < cnt && lane < 16)
                   ? __expf(leaky(asrc2[sv] + ad)) : 0.f;
    zacc += pv;
    // phase 1: 16 unconditional row loads (clamped SGPR bases, padded rows hit L1)
    _Float16 u[16];
    #pragma unroll
    for (int e = 0; e < 16; ++e){
      int s = __builtin_amdgcn_readfirstlane(__shfl(sv, e, 64));
      u[e] = xp2[(size_t)s*XPAD + lane];
    }
    __builtin_amdgcn_sched_barrier(0);   // pin: all 16 loads before any FMA
    // phase 2: fma (p = 0 for padded)
    #pragma unroll
    for (int e = 0; e < 16; ++e){
      const float p = __shfl(pv, e, 64);
      acc += p * (float)u[e];
    }
  }
  #pragma unroll
  for (int off = 1; off < 64; off <<= 1) zacc += __shfl_xor(zacc, off, 64);

  float val = act ? (acc/(zacc + 1e-16f) + b2[lane]) : -INFINITY;
  float m = val;
  #pragma unroll
  for (int off = 32; off > 0; off >>= 1) m = fmaxf(m, __shfl_xor(m, off, 64));
  float e = act ? __expf(val - m) : 0.f;
  float sum = e;
  #pragma unroll
  for (int off = 32; off > 0; off >>= 1) sum += __shfl_xor(sum, off, 64);
  if (act) out[(size_t)n*OC + lane] = val - m - __logf(sum);
}

extern "C" void kernel_launch(void* const* d_in, const int* in_sizes, int n_in,
                              void* d_out, int out_size, void* d_ws, size_t ws_size,
                              hipStream_t stream)
{
  const float* x   = (const float*)d_in[0];
  const int*   ei  = (const int*)  d_in[1];
  const float* W1  = (const float*)d_in[2];
  const float* aS1 = (const float*)d_in[3];
  const float* aD1 = (const float*)d_in[4];
  const float* b1  = (const float*)d_in[5];
  const float* W2  = (const float*)d_in[6];
  const float* aS2 = (const float*)d_in[7];
  const float* aD2 = (const float*)d_in[8];
  const float* b2  = (const float*)d_in[9];
  float* out = (float*)d_out;

  char* wsp = (char*)d_ws;
  size_t off = 0;
  auto alloc = [&](size_t bytes){ void* p = wsp + off; off += (bytes + 255) & ~(size_t)255; return p; };
  unsigned* xp1w = (unsigned*)alloc((size_t)NN*C1);            // fp8, permuted, 64 dwords/row
  _Float16* h1  = (_Float16*)alloc((size_t)NN*C1*2);           // fp16, permuted cols
  float* as1  = (float*)alloc((size_t)NN*8*4);
  float* ad1  = (float*)alloc((size_t)NN*8*4);
  float* as2  = (float*)alloc((size_t)NN*4);
  float* ad2  = (float*)alloc((size_t)NN*4);
  int* deg    = (int*)alloc((size_t)NN*4);
  int* part   = (int*)alloc((size_t)NN*4);
  int* rowptr = (int*)alloc((size_t)(NN+1)*4);
  int* cursor = (int*)alloc((size_t)NN*4);
  int* bsum   = (int*)alloc(98*4);
  int* boff   = (int*)alloc(98*4);
  int* esrc   = (int*)alloc((size_t)(NN+NE)*4);
  _Float16* W1t = (_Float16*)alloc((size_t)256*128*2);
  _Float16* W2t = (_Float16*)alloc((size_t)48*256*2);
  _Float16* xp2 = (_Float16*)alloc((size_t)NN*XPAD*2);  // 12.8 MB, 128B-aligned rows
  (void)ws_size; (void)in_sizes; (void)n_in; (void)out_size;

  k_wt       <<<176,  256, 0, stream>>>(W1, W2, W1t, W2t);
  k_gemm1    <<<1563, 256, 0, stream>>>(x, W1t, aS1, aD1, xp1w, as1, ad1);
  k_deg_init <<<391,  256, 0, stream>>>(deg);
  k_deg_count<<<3125, 256, 0, stream>>>(ei, deg);
  k_scan1    <<<98,   256, 0, stream>>>(deg, part, bsum);
  k_scan2    <<<1,    64,  0, stream>>>(bsum, boff);
  k_scan3    <<<391,  256, 0, stream>>>(part, boff, rowptr, cursor);
  k_fill     <<<3516, 256, 0, stream>>>(ei, cursor, esrc);
  k_agg1     <<<25000,256, 0, stream>>>(xp1w, as1, ad1, b1, rowptr, esrc, h1);
  k_gemm2    <<<391,  256, 0, stream>>>(h1, W2t, aS2, aD2, xp2, as2, ad2);
  k_agg2     <<<25000,256, 0, stream>>>(xp2, as2, ad2, b2, rowptr, esrc, out);
}